// Round 1
// baseline (627.377 us; speedup 1.0000x reference)
//
#include <hip/hip_runtime.h>
#include <hip/hip_bf16.h>

// Problem constants
constexpr int Bn   = 128;    // batch
constexpr int In   = 800;    // genes per case
constexpr int En   = 512;    // embed dim
constexpr int V1   = 19001;  // vocab + padding row
constexpr int NHn  = 8;      // heads
constexpr int NBn  = 4;      // attention blocks
constexpr int OUTn = 5000;   // output genes

// d_out layout (floats): preds [B,OUT] | attns [NB,B,I] | hiddens [NB,B,E]
constexpr int OFF_ATTN = Bn * OUTn;                 // 640000
constexpr int OFF_HID  = OFF_ATTN + NBn * Bn * In;  // 1049600

typedef __attribute__((ext_vector_type(8))) short bf16x8;
typedef __attribute__((ext_vector_type(8))) unsigned short u16x8;
typedef __attribute__((ext_vector_type(4))) float f32x4;

__device__ inline ushort f2bf(float x) {
    __hip_bfloat16 h = __float2bfloat16(x);
    return *reinterpret_cast<ushort*>(&h);
}
__device__ inline float bf2f(ushort u) {
    return __uint_as_float(((unsigned)u) << 16);
}
__device__ inline void gl_lds16(const ushort* g, ushort* l) {
    __builtin_amdgcn_global_load_lds(
        (const __attribute__((address_space(1))) void*)g,
        (__attribute__((address_space(3))) void*)l, 16, 0, 0);
}

// fast tanh: 1 - 2/(e^{2x}+1).  Saturates to +-1, no NaN for large |x|.
__device__ inline float fast_tanh(float x) {
    const float e = __expf(2.0f * x);
    return 1.0f - 2.0f / (e + 1.0f);
}

// DPP quad-perm xor-1 / xor-2 (VALU lane exchange, keeps LDS pipe free)
#define DPP_XOR1(x) __int_as_float(__builtin_amdgcn_update_dpp( \
    0, __float_as_int(x), 0xB1, 0xF, 0xF, false))
#define DPP_XOR2(x) __int_as_float(__builtin_amdgcn_update_dpp( \
    0, __float_as_int(x), 0x4E, 0xF, 0xF, false))

// ---------------------------------------------------------------------------
// K0: Wkt[nb][n][k] = bf16(Wk[nb][k][n]) via LDS tile transpose (coalesced IO)
// ---------------------------------------------------------------------------
__global__ __launch_bounds__(256)
void k_prep(const float* __restrict__ Wk, ushort* __restrict__ Wkt) {
    __shared__ float ts[64][65];
    const int n0 = blockIdx.x * 64, k0 = blockIdx.y * 64, nb = blockIdx.z;
    const int t = threadIdx.x;
    {
        const int kr = t >> 2, nc = (t & 3) * 16;
        const float* p = Wk + (((size_t)nb * En) + (k0 + kr)) * En + n0 + nc;
#pragma unroll
        for (int j = 0; j < 4; ++j) {
            const float4 v = *(const float4*)(p + j * 4);
            ts[kr][nc + j * 4 + 0] = v.x; ts[kr][nc + j * 4 + 1] = v.y;
            ts[kr][nc + j * 4 + 2] = v.z; ts[kr][nc + j * 4 + 3] = v.w;
        }
    }
    __syncthreads();
    {
        const int nr = t >> 2, kc = (t & 3) * 16;
        ushort* d = Wkt + (((size_t)nb * En) + (n0 + nr)) * En + k0 + kc;
        ushort4 o;
#pragma unroll
        for (int j = 0; j < 4; ++j) {
            o.x = f2bf(ts[kc + j * 4 + 0][nr]); o.y = f2bf(ts[kc + j * 4 + 1][nr]);
            o.z = f2bf(ts[kc + j * 4 + 2][nr]); o.w = f2bf(ts[kc + j * 4 + 3][nr]);
            *(ushort4*)(d + j * 4) = o;
        }
    }
}

// ---------------------------------------------------------------------------
// K1: scoresv[nb][v][h] from keys = tanh(T@Wk+bk), scores = keys@Wq.
// Block tile M=64 x N=512 (A read exactly once per launch), BK=32, 16 iters,
// double-buffered: glds B[next] + A[next]->regs issued before current MFMAs.
// 8 waves (512 thr), wave tile 64x64 (acc[4][4]) -> 80 KB LDS, 2 blk/CU,
// 16 waves/CU (2x the previous occupancy at identical memory traffic).
// Epilogue: fast-tanh + per-head VALU dot + DPP/shfl butterfly + cross-wave
// LDS reduce -> direct scoresv stores.  TBF: side-store bf16 A rows for k_emb.
// ---------------------------------------------------------------------------
template <bool TBF>
__global__ __launch_bounds__(512, 4)
void k_scores(const float* __restrict__ T, const ushort* __restrict__ Wkt,
              const float* __restrict__ bk, const float* __restrict__ Wq,
              float* __restrict__ scoresv, ushort* __restrict__ Tbf) {
    __shared__ ushort Bs[2][512][32];                                    // 64 KB
    __shared__ union { ushort A[2][64][32]; float red[8][64][NHn]; } u;  // 16 KB

    const int mblk = blockIdx.x, nb = blockIdx.y;
    const int v0 = mblk * 64;
    const int tid = threadIdx.x, lane = tid & 63, w = tid >> 6;  // w in 0..7
    const int q = lane >> 4, c = lane & 15;

    const float*  Tb = T + (size_t)nb * V1 * En;
    const ushort* Wn = Wkt + (size_t)nb * En * En;

    // A staging map: thread t -> row t>>3 (0..63), 4-float chunk t&7
    const int arow = tid >> 3, akq = tid & 7;
    const int vra = v0 + arow;
    const float* agp = Tb + (size_t)vra * En + akq * 4;
    ushort* tsp = Tbf + ((size_t)nb * V1 + vra) * En + akq * 4;

    f32x4 acc[4][4];
#pragma unroll
    for (int mt = 0; mt < 4; ++mt)
#pragma unroll
        for (int nt = 0; nt < 4; ++nt) acc[mt][nt] = (f32x4)0.0f;

    auto stageB = [&](int buf, int k0) {
#pragma unroll
        for (int j = 0; j < 4; ++j) {
            const int nrow = (w * 4 + j) * 16;
            const ushort* gp =
                Wn + (size_t)(nrow + (lane >> 2)) * En + k0 + (lane & 3) * 8;
            gl_lds16(gp, &Bs[buf][nrow][0]);
        }
    };
    auto loadA = [&](int k0, float4& f0) {
        if (vra < V1) f0 = *(const float4*)(agp + k0);
        else          f0 = make_float4(0.f, 0.f, 0.f, 0.f);
    };
    auto writeA = [&](int buf, int k0, float4 f0) {
        ushort4 o;
        o.x = f2bf(f0.x); o.y = f2bf(f0.y); o.z = f2bf(f0.z); o.w = f2bf(f0.w);
        *(ushort4*)&u.A[buf][arow][akq * 4] = o;
        if (TBF && vra < V1) *(ushort4*)(tsp + k0) = o;
    };

    // prologue: stage iteration 0
    stageB(0, 0);
    {
        float4 f0;
        loadA(0, f0);
        writeA(0, 0, f0);
    }
    __syncthreads();

    for (int it = 0; it < 16; ++it) {
        const int cur = it & 1, nxt = cur ^ 1;
        const int k0n = (it + 1) * 32;
        float4 p0;
        if (it < 15) {
            stageB(nxt, k0n);   // async into other buffer, no wait
            loadA(k0n, p0);     // prefetch A into regs, no use yet
        }
        bf16x8 aF[4], bF[4];
#pragma unroll
        for (int mt = 0; mt < 4; ++mt)
            aF[mt] = *(bf16x8*)&u.A[cur][mt * 16 + c][q * 8];
#pragma unroll
        for (int nt = 0; nt < 4; ++nt)
            bF[nt] = *(bf16x8*)&Bs[cur][w * 64 + nt * 16 + c][q * 8];
#pragma unroll
        for (int nt = 0; nt < 4; ++nt)
#pragma unroll
            for (int mt = 0; mt < 4; ++mt)
                acc[mt][nt] = __builtin_amdgcn_mfma_f32_16x16x32_bf16(
                    aF[mt], bF[nt], acc[mt][nt], 0, 0, 0);
        if (it < 15) writeA(nxt, k0n, p0);
        __syncthreads();  // drains glds B[nxt] + A writes; overlapped w/ MFMAs
    }

    // --- epilogue: keys = tanh(acc + bk[col]) in-register (fast tanh) ---
#pragma unroll
    for (int nt = 0; nt < 4; ++nt) {
        const int col = w * 64 + nt * 16 + c;
        const float bkv = bk[nb * En + col];
#pragma unroll
        for (int mt = 0; mt < 4; ++mt)
#pragma unroll
            for (int r = 0; r < 4; ++r)
                acc[mt][nt][r] = fast_tanh(acc[mt][nt][r] + bkv);
    }

    // --- scores: per head, dot over this wave's 64 cols, then reduce the
    //     16 c-lanes: xor1/xor2 via DPP (VALU), xor4/xor8 via swizzle.
    for (int h = 0; h < NHn; ++h) {
        float wqh[4];
#pragma unroll
        for (int nt = 0; nt < 4; ++nt) {
            const int col = w * 64 + nt * 16 + c;
            wqh[nt] = Wq[((size_t)nb * En + col) * NHn + h];
        }
        float p[4][4];
#pragma unroll
        for (int mt = 0; mt < 4; ++mt)
#pragma unroll
            for (int r = 0; r < 4; ++r) {
                float s = 0.f;
#pragma unroll
                for (int nt = 0; nt < 4; ++nt) s += acc[mt][nt][r] * wqh[nt];
                s += DPP_XOR1(s);
                s += DPP_XOR2(s);
                s += __shfl_xor(s, 4, 64);
                s += __shfl_xor(s, 8, 64);
                p[mt][r] = s;
            }
        if (c == h) {
#pragma unroll
            for (int mt = 0; mt < 4; ++mt)
#pragma unroll
                for (int r = 0; r < 4; ++r)
                    u.red[w][mt * 16 + q * 4 + r][h] = p[mt][r];
        }
    }
    __syncthreads();

    // --- cross-wave reduce, direct store (bq dropped: cancels in softmax) ---
    {
        const int row = tid >> 3, h = tid & 7;   // 512 threads == 64*8 entries
        const int vr = v0 + row;
        if (vr < V1) {
            float s = 0.f;
#pragma unroll
            for (int wv = 0; wv < 8; ++wv) s += u.red[wv][row][h];
            scoresv[((size_t)nb * V1 + vr) * NHn + h] = s;
        }
    }
}

// ---------------------------------------------------------------------------
// K2: masked softmax over genes, per (nb, b); writes attn weights (head-sum).
// ---------------------------------------------------------------------------
__global__ __launch_bounds__(256)
void k_softmax(const int* __restrict__ sga, const float* __restrict__ scoresv,
               float* __restrict__ attn_out) {
    const int b  = blockIdx.x;
    const int nb = blockIdx.y;
    const int tid = threadIdx.x;
    const int lane = tid & 63;
    const int wid  = tid >> 6;
    __shared__ float red[4 * NHn];

    float sc[4][NHn];
    int ivals[4];
#pragma unroll
    for (int s = 0; s < 4; ++s) {
        const int i = tid + s * 256;
        ivals[s] = i;
        if (i < In) {
            const int v = sga[b * In + i];
            const float4 s0 = *(const float4*)(scoresv + ((size_t)nb * V1 + v) * NHn);
            const float4 s1 = *(const float4*)(scoresv + ((size_t)nb * V1 + v) * NHn + 4);
            sc[s][0] = s0.x; sc[s][1] = s0.y; sc[s][2] = s0.z; sc[s][3] = s0.w;
            sc[s][4] = s1.x; sc[s][5] = s1.y; sc[s][6] = s1.z; sc[s][7] = s1.w;
            if (v == 0) {
#pragma unroll
                for (int n = 0; n < NHn; ++n) sc[s][n] = -1e9f;
            }
        } else {
#pragma unroll
            for (int n = 0; n < NHn; ++n) sc[s][n] = -3.0e38f;
        }
    }

    float lm[NHn];
#pragma unroll
    for (int n = 0; n < NHn; ++n)
        lm[n] = fmaxf(fmaxf(sc[0][n], sc[1][n]), fmaxf(sc[2][n], sc[3][n]));
#pragma unroll
    for (int m = 1; m < 64; m <<= 1) {
#pragma unroll
        for (int n = 0; n < NHn; ++n) lm[n] = fmaxf(lm[n], __shfl_xor(lm[n], m, 64));
    }
    if (lane == 0) {
#pragma unroll
        for (int n = 0; n < NHn; ++n) red[wid * NHn + n] = lm[n];
    }
    __syncthreads();
    float M[NHn];
#pragma unroll
    for (int n = 0; n < NHn; ++n)
        M[n] = fmaxf(fmaxf(red[n], red[NHn + n]), fmaxf(red[2 * NHn + n], red[3 * NHn + n]));
    __syncthreads();

    float ls[NHn];
#pragma unroll
    for (int n = 0; n < NHn; ++n) ls[n] = 0.f;
#pragma unroll
    for (int s = 0; s < 4; ++s) {
#pragma unroll
        for (int n = 0; n < NHn; ++n) {
            sc[s][n] = expf(sc[s][n] - M[n]);
            ls[n] += sc[s][n];
        }
    }
#pragma unroll
    for (int m = 1; m < 64; m <<= 1) {
#pragma unroll
        for (int n = 0; n < NHn; ++n) ls[n] += __shfl_xor(ls[n], m, 64);
    }
    if (lane == 0) {
#pragma unroll
        for (int n = 0; n < NHn; ++n) red[wid * NHn + n] = ls[n];
    }
    __syncthreads();
    float inv[NHn];
#pragma unroll
    for (int n = 0; n < NHn; ++n) {
        const float S = red[n] + red[NHn + n] + red[2 * NHn + n] + red[3 * NHn + n];
        inv[n] = 1.0f / S;
    }

#pragma unroll
    for (int s = 0; s < 4; ++s) {
        if (ivals[s] < In) {
            float w = 0.f;
#pragma unroll
            for (int n = 0; n < NHn; ++n) w += sc[s][n] * inv[n];
            attn_out[((size_t)nb * Bn + b) * In + ivals[s]] = w;
        }
    }
}

// ---------------------------------------------------------------------------
// K3: emb[nb][b][e] = sum_i w[nb,b,i] * T[nb][sga[b,i]][e]
// 512 threads = 8 waves x 100 genes; LDS partial reduce.
// TBF variant gathers bf16 rows (half the L3 traffic).  unroll 10 keeps 10
// independent 1KB row-gathers in flight per wave (latency hiding).
// ---------------------------------------------------------------------------
template <bool TBF>
__global__ __launch_bounds__(512)
void k_emb(const int* __restrict__ sga, const float* __restrict__ attn,
           const float* __restrict__ T, const ushort* __restrict__ Tbf,
           float* __restrict__ emb) {
    const int b  = blockIdx.x;
    const int nb = blockIdx.y;
    __shared__ int   sv[In];
    __shared__ float sw[In];
    __shared__ float pa[8][En];  // 16 KB
    for (int idx = threadIdx.x; idx < In; idx += 512) {
        sv[idx] = sga[b * In + idx];
        sw[idx] = attn[((size_t)nb * Bn + b) * In + idx];
    }
    __syncthreads();
    const int wave = threadIdx.x >> 6, lane = threadIdx.x & 63;
    float a[8];
#pragma unroll
    for (int j = 0; j < 8; ++j) a[j] = 0.f;

    if (TBF) {
        const ushort* Tb = Tbf + (size_t)nb * V1 * En;
#pragma unroll 10
        for (int g = 0; g < 100; ++g) {
            const int i = wave * 100 + g;
            const int v = sv[i];
            const float w = sw[i];
            const u16x8 t = *(const u16x8*)(Tb + (size_t)v * En + lane * 8);
#pragma unroll
            for (int j = 0; j < 8; ++j) a[j] += w * bf2f(t[j]);
        }
    } else {
        const float* Tb = T + (size_t)nb * V1 * En;
#pragma unroll 10
        for (int g = 0; g < 100; ++g) {
            const int i = wave * 100 + g;
            const int v = sv[i];
            const float w = sw[i];
            const float4* p = (const float4*)(Tb + (size_t)v * En) + lane * 2;
            const float4 t0 = p[0], t1 = p[1];
            a[0] += w * t0.x; a[1] += w * t0.y; a[2] += w * t0.z; a[3] += w * t0.w;
            a[4] += w * t1.x; a[5] += w * t1.y; a[6] += w * t1.z; a[7] += w * t1.w;
        }
    }
#pragma unroll
    for (int j = 0; j < 8; ++j) pa[wave][lane * 8 + j] = a[j];
    __syncthreads();
    const int t = threadIdx.x;
    float s = 0.f;
#pragma unroll
    for (int wv = 0; wv < 8; ++wv) s += pa[wv][t];
    emb[((size_t)nb * Bn + b) * En + t] = s;
}

// ---------------------------------------------------------------------------
// K4a: curr0 = relu(emb0 + can_emb[can]); hiddens[0] = curr0
// ---------------------------------------------------------------------------
__global__ __launch_bounds__(256)
void k_step0(const float* __restrict__ emb0, const int* __restrict__ can,
             const float* __restrict__ can_emb, float* __restrict__ cur,
             float* __restrict__ hid) {
    const int b = blockIdx.x;
    const int e0 = threadIdx.x * 2;
    const int c = can[b];
    float2 v = *(const float2*)(emb0 + (size_t)b * En + e0);
    const float2 ce = *(const float2*)(can_emb + (size_t)c * En + e0);
    v.x = fmaxf(v.x + ce.x, 0.f);
    v.y = fmaxf(v.y + ce.y, 0.f);
    *(float2*)(cur + (size_t)b * En + e0) = v;
    *(float2*)(hid + (size_t)b * En + e0) = v;
}

// ---------------------------------------------------------------------------
// K4b: curr = act(emb_i + prev @ Wh), K-split over 2 half-ranges,
// grid (b, 4 col-chunks) = 512 blocks.  act: 0=relu, 1=sigmoid
// ---------------------------------------------------------------------------
__global__ __launch_bounds__(256)
void k_step(const float* __restrict__ embi, const float* __restrict__ prev,
            const float* __restrict__ Whi, float* __restrict__ cur,
            float* __restrict__ hid, const int sig) {
    const int b = blockIdx.x, cc = blockIdx.y;
    __shared__ float pr[En];
    __shared__ float part[2][128];
    pr[threadIdx.x]       = prev[(size_t)b * En + threadIdx.x];
    pr[threadIdx.x + 256] = prev[(size_t)b * En + threadIdx.x + 256];
    __syncthreads();
    const int col = cc * 128 + (threadIdx.x & 127);
    const int kh  = threadIdx.x >> 7;
    float s = 0.f;
    const float* Wp = Whi + (size_t)(kh * 256) * En + col;
#pragma unroll 8
    for (int k = 0; k < 256; ++k) s += pr[kh * 256 + k] * Wp[(size_t)k * En];
    part[kh][threadIdx.x & 127] = s;
    __syncthreads();
    if (threadIdx.x < 128) {
        float a = part[0][threadIdx.x] + part[1][threadIdx.x] +
                  embi[(size_t)b * En + col];
        if (sig) a = 1.0f / (1.0f + expf(-a));
        else     a = fmaxf(a, 0.f);
        cur[(size_t)b * En + col] = a;
        hid[(size_t)b * En + col] = a;
    }
}

// ---------------------------------------------------------------------------
// K5: preds = curr3 @ Wfinal   [128,512]@[512,5000]
// ---------------------------------------------------------------------------
__global__ __launch_bounds__(256, 2)
void k_preds(const float* __restrict__ cur, const float* __restrict__ Wf,
             float* __restrict__ preds) {
    __shared__ float cs[32 * En];  // 64 KB
    const int nt = blockIdx.x;
    const int bt = blockIdx.y;
    for (int idx = threadIdx.x; idx < 32 * 128; idx += 256) {
        const int row = idx >> 7;
        const int c4  = (idx & 127) << 2;
        *(float4*)(cs + row * En + c4) =
            *(const float4*)(cur + (size_t)(bt * 32 + row) * En + c4);
    }
    __syncthreads();
    const int lane = threadIdx.x & 63;
    const int rgrp = threadIdx.x >> 6;
    const int col = nt * 64 + lane;
    float acc[8];
#pragma unroll
    for (int j = 0; j < 8; ++j) acc[j] = 0.f;
    const bool ok = (col < OUTn);
    for (int k = 0; k < En; k += 4) {
        float w0 = 0.f, w1 = 0.f, w2 = 0.f, w3 = 0.f;
        if (ok) {
            w0 = Wf[(size_t)(k + 0) * OUTn + col];
            w1 = Wf[(size_t)(k + 1) * OUTn + col];
            w2 = Wf[(size_t)(k + 2) * OUTn + col];
            w3 = Wf[(size_t)(k + 3) * OUTn + col];
        }
#pragma unroll
        for (int j = 0; j < 8; ++j) {
            const float4 cv = *(const float4*)(cs + (rgrp * 8 + j) * En + k);
            acc[j] += cv.x * w0 + cv.y * w1 + cv.z * w2 + cv.w * w3;
        }
    }
    if (ok) {
#pragma unroll
        for (int j = 0; j < 8; ++j)
            preds[(size_t)(bt * 32 + rgrp * 8 + j) * OUTn + col] = acc[j];
    }
}

// ---------------------------------------------------------------------------
extern "C" void kernel_launch(void* const* d_in, const int* in_sizes, int n_in,
                              void* d_out, int out_size, void* d_ws, size_t ws_size,
                              hipStream_t stream) {
    const int*   sga     = (const int*)d_in[0];
    const int*   can     = (const int*)d_in[1];
    const float* T       = (const float*)d_in[2];
    const float* Wk      = (const float*)d_in[3];
    const float* bk      = (const float*)d_in[4];
    const float* Wq      = (const float*)d_in[5];
    // d_in[6] = bq: unused — constant over softmax axis, cancels exactly
    const float* can_emb = (const float*)d_in[7];
    const float* Wh      = (const float*)d_in[8];
    const float* Wf      = (const float*)d_in[9];

    float* out = (float*)d_out;
    float* ws  = (float*)d_ws;

    // workspace layout (floats; all 16B-aligned)
    float* scoresv = ws;                                // NB*V1*NH   = 608032
    float* embw    = scoresv + (size_t)NBn * V1 * NHn;  // NB*B*E     = 262144
    float* cur0    = embw + (size_t)NBn * Bn * En;      // B*E
    float* cur1    = cur0 + (size_t)Bn * En;            // B*E
    ushort* Wkt    = (ushort*)(cur1 + (size_t)Bn * En); // NB*E*E bf16 = 2 MB
    ushort* Tbf    = Wkt + (size_t)NBn * En * En;       // NB*V1*E bf16 = 78 MB
    const size_t need_full =
        (size_t)(scoresv - ws) * 4 +
        ((size_t)NBn * V1 * NHn + (size_t)NBn * Bn * En + 2 * (size_t)Bn * En) * 4 +
        (size_t)NBn * En * En * 2 + (size_t)NBn * V1 * En * 2;
    const bool useTbf = (ws_size >= need_full);

    float* preds_out = out;
    float* attn_out  = out + OFF_ATTN;
    float* hid_out   = out + OFF_HID;

    // K0: Wk -> bf16 transposed [nb][n][k]
    k_prep<<<dim3(8, 8, NBn), 256, 0, stream>>>(Wk, Wkt);
    // K1: fused keys-GEMM + scores epilogue (direct stores, no atomics)
    if (useTbf)
        k_scores<true><<<dim3((V1 + 63) / 64, NBn), 512, 0, stream>>>(
            T, Wkt, bk, Wq, scoresv, Tbf);
    else
        k_scores<false><<<dim3((V1 + 63) / 64, NBn), 512, 0, stream>>>(
            T, Wkt, bk, Wq, scoresv, Tbf);
    // K2: softmax + head-sum -> attns (directly to d_out)
    k_softmax<<<dim3(Bn, NBn), 256, 0, stream>>>(sga, scoresv, attn_out);
    // K3: weighted embedding sums (bf16 gather if Tbf available)
    if (useTbf)
        k_emb<true><<<dim3(Bn, NBn), 512, 0, stream>>>(sga, attn_out, T, Tbf, embw);
    else
        k_emb<false><<<dim3(Bn, NBn), 512, 0, stream>>>(sga, attn_out, T, Tbf, embw);
    // K4: residual chain
    k_step0<<<Bn, 256, 0, stream>>>(embw, can, can_emb, cur0, hid_out);
    k_step<<<dim3(Bn, 4), 256, 0, stream>>>(embw + 1 * Bn * En, cur0,
                                            Wh + 0 * En * En, cur1,
                                            hid_out + 1 * (size_t)Bn * En, 0);
    k_step<<<dim3(Bn, 4), 256, 0, stream>>>(embw + 2 * Bn * En, cur1,
                                            Wh + 1 * En * En, cur0,
                                            hid_out + 2 * (size_t)Bn * En, 0);
    k_step<<<dim3(Bn, 4), 256, 0, stream>>>(embw + 3 * Bn * En, cur0,
                                            Wh + 2 * En * En, cur1,
                                            hid_out + 3 * (size_t)Bn * En, 1);
    // K5: final projection
    k_preds<<<dim3((OUTn + 63) / 64, Bn / 32), 256, 0, stream>>>(cur1, Wf, preds_out);
}

// Round 2
// 544.923 us; speedup vs baseline: 1.1513x; 1.1513x over previous
//
#include <hip/hip_runtime.h>
#include <hip/hip_bf16.h>

// Problem constants
constexpr int Bn   = 128;    // batch
constexpr int In   = 800;    // genes per case
constexpr int En   = 512;    // embed dim
constexpr int V1   = 19001;  // vocab + padding row
constexpr int NHn  = 8;      // heads
constexpr int NBn  = 4;      // attention blocks
constexpr int OUTn = 5000;   // output genes

// d_out layout (floats): preds [B,OUT] | attns [NB,B,I] | hiddens [NB,B,E]
constexpr int OFF_ATTN = Bn * OUTn;                 // 640000
constexpr int OFF_HID  = OFF_ATTN + NBn * Bn * In;  // 1049600

typedef __attribute__((ext_vector_type(8))) short bf16x8;
typedef __attribute__((ext_vector_type(8))) unsigned short u16x8;
typedef __attribute__((ext_vector_type(4))) float f32x4;

__device__ inline ushort f2bf(float x) {
    __hip_bfloat16 h = __float2bfloat16(x);
    return *reinterpret_cast<ushort*>(&h);
}
__device__ inline float bf2f(ushort u) {
    return __uint_as_float(((unsigned)u) << 16);
}
__device__ inline void gl_lds16(const ushort* g, ushort* l) {
    __builtin_amdgcn_global_load_lds(
        (const __attribute__((address_space(1))) void*)g,
        (__attribute__((address_space(3))) void*)l, 16, 0, 0);
}

// fast tanh: 1 - 2/(e^{2x}+1).  Saturates to +-1, no NaN for large |x|.
__device__ inline float fast_tanh(float x) {
    const float e = __expf(2.0f * x);
    return 1.0f - 2.0f / (e + 1.0f);
}

// DPP quad-perm xor-1 / xor-2 (VALU lane exchange, keeps LDS pipe free)
#define DPP_XOR1(x) __int_as_float(__builtin_amdgcn_update_dpp( \
    0, __float_as_int(x), 0xB1, 0xF, 0xF, false))
#define DPP_XOR2(x) __int_as_float(__builtin_amdgcn_update_dpp( \
    0, __float_as_int(x), 0x4E, 0xF, 0xF, false))

// ---------------------------------------------------------------------------
// K0: Wkt[nb][n][k] = bf16(Wk[nb][k][n]) via LDS tile transpose (coalesced IO)
// ---------------------------------------------------------------------------
__global__ __launch_bounds__(256)
void k_prep(const float* __restrict__ Wk, ushort* __restrict__ Wkt) {
    __shared__ float ts[64][65];
    const int n0 = blockIdx.x * 64, k0 = blockIdx.y * 64, nb = blockIdx.z;
    const int t = threadIdx.x;
    {
        const int kr = t >> 2, nc = (t & 3) * 16;
        const float* p = Wk + (((size_t)nb * En) + (k0 + kr)) * En + n0 + nc;
#pragma unroll
        for (int j = 0; j < 4; ++j) {
            const float4 v = *(const float4*)(p + j * 4);
            ts[kr][nc + j * 4 + 0] = v.x; ts[kr][nc + j * 4 + 1] = v.y;
            ts[kr][nc + j * 4 + 2] = v.z; ts[kr][nc + j * 4 + 3] = v.w;
        }
    }
    __syncthreads();
    {
        const int nr = t >> 2, kc = (t & 3) * 16;
        ushort* d = Wkt + (((size_t)nb * En) + (n0 + nr)) * En + k0 + kc;
        ushort4 o;
#pragma unroll
        for (int j = 0; j < 4; ++j) {
            o.x = f2bf(ts[kc + j * 4 + 0][nr]); o.y = f2bf(ts[kc + j * 4 + 1][nr]);
            o.z = f2bf(ts[kc + j * 4 + 2][nr]); o.w = f2bf(ts[kc + j * 4 + 3][nr]);
            *(ushort4*)(d + j * 4) = o;
        }
    }
}

// ---------------------------------------------------------------------------
// K1: scoresv[nb][v][h] from keys = tanh(T@Wk+bk), scores = keys@Wq.
// Round-0 shape restored: 256 thr / 4 waves, wave tile 64x128 (acc[4][8]),
// BK=32, 16 iters, double-buffered glds B + reg-prefetched A.
// New this round:
//  - XOR granule swizzle (g ^= row&3) on Bs and A tiles: 8-way -> 4-way bank
//    conflicts on every ds_read_b128.  B is swizzled via pre-swizzled GLOBAL
//    source (glds dest must stay linear); A via swizzled ds_write.
//  - Paired Tbf stores: even-iter bf16 chunk stashed in regs, stored together
//    with the odd-iter chunk -> every 128B line fully written back-to-back
//    (kills partial-line writeback/write-allocate amplification).
//  - fast_tanh + DPP xor1/2 butterfly in epilogue.
// ---------------------------------------------------------------------------
template <bool TBF>
__global__ __launch_bounds__(256, 2)
void k_scores(const float* __restrict__ T, const ushort* __restrict__ Wkt,
              const float* __restrict__ bk, const float* __restrict__ Wq,
              float* __restrict__ scoresv, ushort* __restrict__ Tbf) {
    __shared__ ushort Bs[2][512][32];                                  // 64 KB
    __shared__ union { ushort A[2][64][32]; float red[4][64][NHn]; } u;  // 8 KB

    const int mblk = blockIdx.x, nb = blockIdx.y;
    const int v0 = mblk * 64;
    const int tid = threadIdx.x, lane = tid & 63, w = tid >> 6;
    const int q = lane >> 4, c = lane & 15;
    const int gsw = (q ^ (c & 3)) * 8;   // swizzled granule offset for reads

    const float*  Tb = T + (size_t)nb * V1 * En;
    const ushort* Wn = Wkt + (size_t)nb * En * En;

    // A staging map: thread t -> row t>>2 (0..63), 8-float chunk t&3
    const int arow = tid >> 2, akq = tid & 3;
    const int aswz = (akq ^ (arow & 3)) * 8;  // swizzled LDS write offset
    const int vra = v0 + arow;
    const float* agp = Tb + (size_t)vra * En + akq * 8;
    ushort* tsp = Tbf + ((size_t)nb * V1 + vra) * En + akq * 8;

    f32x4 acc[4][8];
#pragma unroll
    for (int mt = 0; mt < 4; ++mt)
#pragma unroll
        for (int nt = 0; nt < 8; ++nt) acc[mt][nt] = (f32x4)0.0f;

    auto stageB = [&](int buf, int k0) {
#pragma unroll
        for (int j = 0; j < 8; ++j) {
            const int nrow = (w * 8 + j) * 16;
            const int r = nrow + (lane >> 2);
            const int gf = (lane & 3) ^ ((lane >> 2) & 3);  // pre-swizzled src
            const ushort* gp = Wn + (size_t)r * En + k0 + gf * 8;
            gl_lds16(gp, &Bs[buf][nrow][0]);
        }
    };
    auto loadA = [&](int k0, float4& f0, float4& f1) {
        if (vra < V1) {
            f0 = *(const float4*)(agp + k0);
            f1 = *(const float4*)(agp + k0 + 4);
        } else {
            f0 = make_float4(0.f, 0.f, 0.f, 0.f);
            f1 = f0;
        }
    };
    u16x8 stash;   // even-iter Tbf chunk, stored paired with the odd iter
    auto writeA = [&](int buf, int k0, float4 f0, float4 f1) {
        u16x8 o;
        o[0] = f2bf(f0.x); o[1] = f2bf(f0.y); o[2] = f2bf(f0.z); o[3] = f2bf(f0.w);
        o[4] = f2bf(f1.x); o[5] = f2bf(f1.y); o[6] = f2bf(f1.z); o[7] = f2bf(f1.w);
        *(u16x8*)&u.A[buf][arow][aswz] = o;
        if (TBF && vra < V1) {
            const int itIdx = k0 >> 5;
            if ((itIdx & 1) == 0) {
                stash = o;
            } else {
                *(u16x8*)(tsp + k0 - 32) = stash;   // back-to-back: full 128B
                *(u16x8*)(tsp + k0)      = o;       // line per row per pair
            }
        }
    };

    // prologue: stage iteration 0
    stageB(0, 0);
    {
        float4 f0, f1;
        loadA(0, f0, f1);
        writeA(0, 0, f0, f1);
    }
    __syncthreads();

    for (int it = 0; it < 16; ++it) {
        const int cur = it & 1, nxt = cur ^ 1;
        const int k0n = (it + 1) * 32;
        float4 p0, p1;
        if (it < 15) {
            stageB(nxt, k0n);   // async into other buffer, no wait
            loadA(k0n, p0, p1); // prefetch A into regs, no use yet
        }
        bf16x8 aF[4], bF[8];
#pragma unroll
        for (int mt = 0; mt < 4; ++mt)
            aF[mt] = *(bf16x8*)&u.A[cur][mt * 16 + c][gsw];
#pragma unroll
        for (int nt = 0; nt < 8; ++nt)
            bF[nt] = *(bf16x8*)&Bs[cur][w * 128 + nt * 16 + c][gsw];
#pragma unroll
        for (int nt = 0; nt < 8; ++nt)
#pragma unroll
            for (int mt = 0; mt < 4; ++mt)
                acc[mt][nt] = __builtin_amdgcn_mfma_f32_16x16x32_bf16(
                    aF[mt], bF[nt], acc[mt][nt], 0, 0, 0);
        if (it < 15) writeA(nxt, k0n, p0, p1);
        __syncthreads();  // drains glds B[nxt] + A writes; overlapped w/ MFMAs
    }

    // --- epilogue: keys = tanh(acc + bk[col]) in-register (fast tanh) ---
#pragma unroll
    for (int nt = 0; nt < 8; ++nt) {
        const int col = w * 128 + nt * 16 + c;
        const float bkv = bk[nb * En + col];
#pragma unroll
        for (int mt = 0; mt < 4; ++mt)
#pragma unroll
            for (int r = 0; r < 4; ++r)
                acc[mt][nt][r] = fast_tanh(acc[mt][nt][r] + bkv);
    }

    // --- scores: per head, dot over this wave's 128 cols; reduce 16 c-lanes
    //     via DPP xor1/xor2 (VALU) + shfl xor4/xor8.
    for (int h = 0; h < NHn; ++h) {
        float wqh[8];
#pragma unroll
        for (int nt = 0; nt < 8; ++nt) {
            const int col = w * 128 + nt * 16 + c;
            wqh[nt] = Wq[((size_t)nb * En + col) * NHn + h];
        }
        float p[4][4];
#pragma unroll
        for (int mt = 0; mt < 4; ++mt)
#pragma unroll
            for (int r = 0; r < 4; ++r) {
                float s = 0.f;
#pragma unroll
                for (int nt = 0; nt < 8; ++nt) s += acc[mt][nt][r] * wqh[nt];
                s += DPP_XOR1(s);
                s += DPP_XOR2(s);
                s += __shfl_xor(s, 4, 64);
                s += __shfl_xor(s, 8, 64);
                p[mt][r] = s;
            }
        if (c == h) {
#pragma unroll
            for (int mt = 0; mt < 4; ++mt)
#pragma unroll
                for (int r = 0; r < 4; ++r)
                    u.red[w][mt * 16 + q * 4 + r][h] = p[mt][r];
        }
    }
    __syncthreads();

    // --- cross-wave reduce, direct store (bq dropped: cancels in softmax) ---
    for (int idx = tid; idx < 64 * NHn; idx += 256) {
        const int row = idx >> 3, h = idx & 7;
        const int vr = v0 + row;
        if (vr < V1)
            scoresv[((size_t)nb * V1 + vr) * NHn + h] =
                u.red[0][row][h] + u.red[1][row][h] +
                u.red[2][row][h] + u.red[3][row][h];
    }
}

// ---------------------------------------------------------------------------
// K2: masked softmax over genes, per (nb, b); writes attn weights (head-sum).
// ---------------------------------------------------------------------------
__global__ __launch_bounds__(256)
void k_softmax(const int* __restrict__ sga, const float* __restrict__ scoresv,
               float* __restrict__ attn_out) {
    const int b  = blockIdx.x;
    const int nb = blockIdx.y;
    const int tid = threadIdx.x;
    const int lane = tid & 63;
    const int wid  = tid >> 6;
    __shared__ float red[4 * NHn];

    float sc[4][NHn];
    int ivals[4];
#pragma unroll
    for (int s = 0; s < 4; ++s) {
        const int i = tid + s * 256;
        ivals[s] = i;
        if (i < In) {
            const int v = sga[b * In + i];
            const float4 s0 = *(const float4*)(scoresv + ((size_t)nb * V1 + v) * NHn);
            const float4 s1 = *(const float4*)(scoresv + ((size_t)nb * V1 + v) * NHn + 4);
            sc[s][0] = s0.x; sc[s][1] = s0.y; sc[s][2] = s0.z; sc[s][3] = s0.w;
            sc[s][4] = s1.x; sc[s][5] = s1.y; sc[s][6] = s1.z; sc[s][7] = s1.w;
            if (v == 0) {
#pragma unroll
                for (int n = 0; n < NHn; ++n) sc[s][n] = -1e9f;
            }
        } else {
#pragma unroll
            for (int n = 0; n < NHn; ++n) sc[s][n] = -3.0e38f;
        }
    }

    float lm[NHn];
#pragma unroll
    for (int n = 0; n < NHn; ++n)
        lm[n] = fmaxf(fmaxf(sc[0][n], sc[1][n]), fmaxf(sc[2][n], sc[3][n]));
#pragma unroll
    for (int m = 1; m < 64; m <<= 1) {
#pragma unroll
        for (int n = 0; n < NHn; ++n) lm[n] = fmaxf(lm[n], __shfl_xor(lm[n], m, 64));
    }
    if (lane == 0) {
#pragma unroll
        for (int n = 0; n < NHn; ++n) red[wid * NHn + n] = lm[n];
    }
    __syncthreads();
    float M[NHn];
#pragma unroll
    for (int n = 0; n < NHn; ++n)
        M[n] = fmaxf(fmaxf(red[n], red[NHn + n]), fmaxf(red[2 * NHn + n], red[3 * NHn + n]));
    __syncthreads();

    float ls[NHn];
#pragma unroll
    for (int n = 0; n < NHn; ++n) ls[n] = 0.f;
#pragma unroll
    for (int s = 0; s < 4; ++s) {
#pragma unroll
        for (int n = 0; n < NHn; ++n) {
            sc[s][n] = expf(sc[s][n] - M[n]);
            ls[n] += sc[s][n];
        }
    }
#pragma unroll
    for (int m = 1; m < 64; m <<= 1) {
#pragma unroll
        for (int n = 0; n < NHn; ++n) ls[n] += __shfl_xor(ls[n], m, 64);
    }
    if (lane == 0) {
#pragma unroll
        for (int n = 0; n < NHn; ++n) red[wid * NHn + n] = ls[n];
    }
    __syncthreads();
    float inv[NHn];
#pragma unroll
    for (int n = 0; n < NHn; ++n) {
        const float S = red[n] + red[NHn + n] + red[2 * NHn + n] + red[3 * NHn + n];
        inv[n] = 1.0f / S;
    }

#pragma unroll
    for (int s = 0; s < 4; ++s) {
        if (ivals[s] < In) {
            float w = 0.f;
#pragma unroll
            for (int n = 0; n < NHn; ++n) w += sc[s][n] * inv[n];
            attn_out[((size_t)nb * Bn + b) * In + ivals[s]] = w;
        }
    }
}

// ---------------------------------------------------------------------------
// K3: emb[nb][b][e] = sum_i w[nb,b,i] * T[nb][sga[b,i]][e]
// 512 threads = 8 waves x 100 genes; LDS partial reduce.
// TBF variant gathers bf16 rows (half the L3 traffic); unroll 10 keeps 10
// independent 1KB row-gathers in flight per wave.
// ---------------------------------------------------------------------------
template <bool TBF>
__global__ __launch_bounds__(512)
void k_emb(const int* __restrict__ sga, const float* __restrict__ attn,
           const float* __restrict__ T, const ushort* __restrict__ Tbf,
           float* __restrict__ emb) {
    const int b  = blockIdx.x;
    const int nb = blockIdx.y;
    __shared__ int   sv[In];
    __shared__ float sw[In];
    __shared__ float pa[8][En];  // 16 KB
    for (int idx = threadIdx.x; idx < In; idx += 512) {
        sv[idx] = sga[b * In + idx];
        sw[idx] = attn[((size_t)nb * Bn + b) * In + idx];
    }
    __syncthreads();
    const int wave = threadIdx.x >> 6, lane = threadIdx.x & 63;
    float a[8];
#pragma unroll
    for (int j = 0; j < 8; ++j) a[j] = 0.f;

    if (TBF) {
        const ushort* Tb = Tbf + (size_t)nb * V1 * En;
#pragma unroll 10
        for (int g = 0; g < 100; ++g) {
            const int i = wave * 100 + g;
            const int v = sv[i];
            const float w = sw[i];
            const u16x8 t = *(const u16x8*)(Tb + (size_t)v * En + lane * 8);
#pragma unroll
            for (int j = 0; j < 8; ++j) a[j] += w * bf2f(t[j]);
        }
    } else {
        const float* Tb = T + (size_t)nb * V1 * En;
#pragma unroll 10
        for (int g = 0; g < 100; ++g) {
            const int i = wave * 100 + g;
            const int v = sv[i];
            const float w = sw[i];
            const float4* p = (const float4*)(Tb + (size_t)v * En) + lane * 2;
            const float4 t0 = p[0], t1 = p[1];
            a[0] += w * t0.x; a[1] += w * t0.y; a[2] += w * t0.z; a[3] += w * t0.w;
            a[4] += w * t1.x; a[5] += w * t1.y; a[6] += w * t1.z; a[7] += w * t1.w;
        }
    }
#pragma unroll
    for (int j = 0; j < 8; ++j) pa[wave][lane * 8 + j] = a[j];
    __syncthreads();
    const int t = threadIdx.x;
    float s = 0.f;
#pragma unroll
    for (int wv = 0; wv < 8; ++wv) s += pa[wv][t];
    emb[((size_t)nb * Bn + b) * En + t] = s;
}

// ---------------------------------------------------------------------------
// K4a: curr0 = relu(emb0 + can_emb[can]); hiddens[0] = curr0
// ---------------------------------------------------------------------------
__global__ __launch_bounds__(256)
void k_step0(const float* __restrict__ emb0, const int* __restrict__ can,
             const float* __restrict__ can_emb, float* __restrict__ cur,
             float* __restrict__ hid) {
    const int b = blockIdx.x;
    const int e0 = threadIdx.x * 2;
    const int c = can[b];
    float2 v = *(const float2*)(emb0 + (size_t)b * En + e0);
    const float2 ce = *(const float2*)(can_emb + (size_t)c * En + e0);
    v.x = fmaxf(v.x + ce.x, 0.f);
    v.y = fmaxf(v.y + ce.y, 0.f);
    *(float2*)(cur + (size_t)b * En + e0) = v;
    *(float2*)(hid + (size_t)b * En + e0) = v;
}

// ---------------------------------------------------------------------------
// K4b: curr = act(emb_i + prev @ Wh), K-split over 2 half-ranges,
// grid (b, 4 col-chunks) = 512 blocks.  act: 0=relu, 1=sigmoid
// ---------------------------------------------------------------------------
__global__ __launch_bounds__(256)
void k_step(const float* __restrict__ embi, const float* __restrict__ prev,
            const float* __restrict__ Whi, float* __restrict__ cur,
            float* __restrict__ hid, const int sig) {
    const int b = blockIdx.x, cc = blockIdx.y;
    __shared__ float pr[En];
    __shared__ float part[2][128];
    pr[threadIdx.x]       = prev[(size_t)b * En + threadIdx.x];
    pr[threadIdx.x + 256] = prev[(size_t)b * En + threadIdx.x + 256];
    __syncthreads();
    const int col = cc * 128 + (threadIdx.x & 127);
    const int kh  = threadIdx.x >> 7;
    float s = 0.f;
    const float* Wp = Whi + (size_t)(kh * 256) * En + col;
#pragma unroll 8
    for (int k = 0; k < 256; ++k) s += pr[kh * 256 + k] * Wp[(size_t)k * En];
    part[kh][threadIdx.x & 127] = s;
    __syncthreads();
    if (threadIdx.x < 128) {
        float a = part[0][threadIdx.x] + part[1][threadIdx.x] +
                  embi[(size_t)b * En + col];
        if (sig) a = 1.0f / (1.0f + expf(-a));
        else     a = fmaxf(a, 0.f);
        cur[(size_t)b * En + col] = a;
        hid[(size_t)b * En + col] = a;
    }
}

// ---------------------------------------------------------------------------
// K5: preds = curr3 @ Wfinal   [128,512]@[512,5000]
// ---------------------------------------------------------------------------
__global__ __launch_bounds__(256, 2)
void k_preds(const float* __restrict__ cur, const float* __restrict__ Wf,
             float* __restrict__ preds) {
    __shared__ float cs[32 * En];  // 64 KB
    const int nt = blockIdx.x;
    const int bt = blockIdx.y;
    for (int idx = threadIdx.x; idx < 32 * 128; idx += 256) {
        const int row = idx >> 7;
        const int c4  = (idx & 127) << 2;
        *(float4*)(cs + row * En + c4) =
            *(const float4*)(cur + (size_t)(bt * 32 + row) * En + c4);
    }
    __syncthreads();
    const int lane = threadIdx.x & 63;
    const int rgrp = threadIdx.x >> 6;
    const int col = nt * 64 + lane;
    float acc[8];
#pragma unroll
    for (int j = 0; j < 8; ++j) acc[j] = 0.f;
    const bool ok = (col < OUTn);
    for (int k = 0; k < En; k += 4) {
        float w0 = 0.f, w1 = 0.f, w2 = 0.f, w3 = 0.f;
        if (ok) {
            w0 = Wf[(size_t)(k + 0) * OUTn + col];
            w1 = Wf[(size_t)(k + 1) * OUTn + col];
            w2 = Wf[(size_t)(k + 2) * OUTn + col];
            w3 = Wf[(size_t)(k + 3) * OUTn + col];
        }
#pragma unroll
        for (int j = 0; j < 8; ++j) {
            const float4 cv = *(const float4*)(cs + (rgrp * 8 + j) * En + k);
            acc[j] += cv.x * w0 + cv.y * w1 + cv.z * w2 + cv.w * w3;
        }
    }
    if (ok) {
#pragma unroll
        for (int j = 0; j < 8; ++j)
            preds[(size_t)(bt * 32 + rgrp * 8 + j) * OUTn + col] = acc[j];
    }
}

// ---------------------------------------------------------------------------
extern "C" void kernel_launch(void* const* d_in, const int* in_sizes, int n_in,
                              void* d_out, int out_size, void* d_ws, size_t ws_size,
                              hipStream_t stream) {
    const int*   sga     = (const int*)d_in[0];
    const int*   can     = (const int*)d_in[1];
    const float* T       = (const float*)d_in[2];
    const float* Wk      = (const float*)d_in[3];
    const float* bk      = (const float*)d_in[4];
    const float* Wq      = (const float*)d_in[5];
    // d_in[6] = bq: unused — constant over softmax axis, cancels exactly
    const float* can_emb = (const float*)d_in[7];
    const float* Wh      = (const float*)d_in[8];
    const float* Wf      = (const float*)d_in[9];

    float* out = (float*)d_out;
    float* ws  = (float*)d_ws;

    // workspace layout (floats; all 16B-aligned)
    float* scoresv = ws;                                // NB*V1*NH   = 608032
    float* embw    = scoresv + (size_t)NBn * V1 * NHn;  // NB*B*E     = 262144
    float* cur0    = embw + (size_t)NBn * Bn * En;      // B*E
    float* cur1    = cur0 + (size_t)Bn * En;            // B*E
    ushort* Wkt    = (ushort*)(cur1 + (size_t)Bn * En); // NB*E*E bf16 = 2 MB
    ushort* Tbf    = Wkt + (size_t)NBn * En * En;       // NB*V1*E bf16 = 78 MB
    const size_t need_full =
        (size_t)(scoresv - ws) * 4 +
        ((size_t)NBn * V1 * NHn + (size_t)NBn * Bn * En + 2 * (size_t)Bn * En) * 4 +
        (size_t)NBn * En * En * 2 + (size_t)NBn * V1 * En * 2;
    const bool useTbf = (ws_size >= need_full);

    float* preds_out = out;
    float* attn_out  = out + OFF_ATTN;
    float* hid_out   = out + OFF_HID;

    // K0: Wk -> bf16 transposed [nb][n][k]
    k_prep<<<dim3(8, 8, NBn), 256, 0, stream>>>(Wk, Wkt);
    // K1: fused keys-GEMM + scores epilogue (direct stores, no atomics)
    if (useTbf)
        k_scores<true><<<dim3((V1 + 63) / 64, NBn), 256, 0, stream>>>(
            T, Wkt, bk, Wq, scoresv, Tbf);
    else
        k_scores<false><<<dim3((V1 + 63) / 64, NBn), 256, 0, stream>>>(
            T, Wkt, bk, Wq, scoresv, Tbf);
    // K2: softmax + head-sum -> attns (directly to d_out)
    k_softmax<<<dim3(Bn, NBn), 256, 0, stream>>>(sga, scoresv, attn_out);
    // K3: weighted embedding sums (bf16 gather if Tbf available)
    if (useTbf)
        k_emb<true><<<dim3(Bn, NBn), 512, 0, stream>>>(sga, attn_out, T, Tbf, embw);
    else
        k_emb<false><<<dim3(Bn, NBn), 512, 0, stream>>>(sga, attn_out, T, Tbf, embw);
    // K4: residual chain
    k_step0<<<Bn, 256, 0, stream>>>(embw, can, can_emb, cur0, hid_out);
    k_step<<<dim3(Bn, 4), 256, 0, stream>>>(embw + 1 * Bn * En, cur0,
                                            Wh + 0 * En * En, cur1,
                                            hid_out + 1 * (size_t)Bn * En, 0);
    k_step<<<dim3(Bn, 4), 256, 0, stream>>>(embw + 2 * Bn * En, cur1,
                                            Wh + 1 * En * En, cur0,
                                            hid_out + 2 * (size_t)Bn * En, 0);
    k_step<<<dim3(Bn, 4), 256, 0, stream>>>(embw + 3 * Bn * En, cur0,
                                            Wh + 2 * En * En, cur1,
                                            hid_out + 3 * (size_t)Bn * En, 1);
    // K5: final projection
    k_preds<<<dim3((OUTn + 63) / 64, Bn / 32), 256, 0, stream>>>(cur1, Wf, preds_out);
}

// Round 3
// 541.741 us; speedup vs baseline: 1.1581x; 1.0059x over previous
//
#include <hip/hip_runtime.h>
#include <hip/hip_bf16.h>

// Problem constants
constexpr int Bn   = 128;    // batch
constexpr int In   = 800;    // genes per case
constexpr int En   = 512;    // embed dim
constexpr int V1   = 19001;  // vocab + padding row
constexpr int NHn  = 8;      // heads
constexpr int NBn  = 4;      // attention blocks
constexpr int OUTn = 5000;   // output genes

// d_out layout (floats): preds [B,OUT] | attns [NB,B,I] | hiddens [NB,B,E]
constexpr int OFF_ATTN = Bn * OUTn;                 // 640000
constexpr int OFF_HID  = OFF_ATTN + NBn * Bn * In;  // 1049600

typedef __attribute__((ext_vector_type(8))) short bf16x8;
typedef __attribute__((ext_vector_type(8))) unsigned short u16x8;
typedef __attribute__((ext_vector_type(4))) float f32x4;

__device__ inline ushort f2bf(float x) {
    __hip_bfloat16 h = __float2bfloat16(x);
    return *reinterpret_cast<ushort*>(&h);
}
__device__ inline float bf2f(ushort u) {
    return __uint_as_float(((unsigned)u) << 16);
}
__device__ inline void gl_lds16(const ushort* g, ushort* l) {
    __builtin_amdgcn_global_load_lds(
        (const __attribute__((address_space(1))) void*)g,
        (__attribute__((address_space(3))) void*)l, 16, 0, 0);
}

// fast tanh: 1 - 2/(e^{2x}+1).  Saturates to +-1, no NaN for large |x|.
__device__ inline float fast_tanh(float x) {
    const float e = __expf(2.0f * x);
    return 1.0f - 2.0f / (e + 1.0f);
}

// DPP quad-perm xor-1 / xor-2 (VALU lane exchange, keeps LDS pipe free)
#define DPP_XOR1(x) __int_as_float(__builtin_amdgcn_update_dpp( \
    0, __float_as_int(x), 0xB1, 0xF, 0xF, false))
#define DPP_XOR2(x) __int_as_float(__builtin_amdgcn_update_dpp( \
    0, __float_as_int(x), 0x4E, 0xF, 0xF, false))

// ---------------------------------------------------------------------------
// K0: Wkt[nb][n][k] = bf16(Wk[nb][k][n]) via LDS tile transpose (coalesced IO)
// ---------------------------------------------------------------------------
__global__ __launch_bounds__(256)
void k_prep(const float* __restrict__ Wk, ushort* __restrict__ Wkt) {
    __shared__ float ts[64][65];
    const int n0 = blockIdx.x * 64, k0 = blockIdx.y * 64, nb = blockIdx.z;
    const int t = threadIdx.x;
    {
        const int kr = t >> 2, nc = (t & 3) * 16;
        const float* p = Wk + (((size_t)nb * En) + (k0 + kr)) * En + n0 + nc;
#pragma unroll
        for (int j = 0; j < 4; ++j) {
            const float4 v = *(const float4*)(p + j * 4);
            ts[kr][nc + j * 4 + 0] = v.x; ts[kr][nc + j * 4 + 1] = v.y;
            ts[kr][nc + j * 4 + 2] = v.z; ts[kr][nc + j * 4 + 3] = v.w;
        }
    }
    __syncthreads();
    {
        const int nr = t >> 2, kc = (t & 3) * 16;
        ushort* d = Wkt + (((size_t)nb * En) + (n0 + nr)) * En + k0 + kc;
        ushort4 o;
#pragma unroll
        for (int j = 0; j < 4; ++j) {
            o.x = f2bf(ts[kc + j * 4 + 0][nr]); o.y = f2bf(ts[kc + j * 4 + 1][nr]);
            o.z = f2bf(ts[kc + j * 4 + 2][nr]); o.w = f2bf(ts[kc + j * 4 + 3][nr]);
            *(ushort4*)(d + j * 4) = o;
        }
    }
}

// ---------------------------------------------------------------------------
// K0b: Tbf = bf16(T), pure streaming at HBM BW (moves the f32 read of T out
// of k_scores' latency-bound loop; write is perfectly streaming-ordered).
// ---------------------------------------------------------------------------
__global__ __launch_bounds__(256)
void k_cvt(const float* __restrict__ T, ushort* __restrict__ Tbf,
           const long long n8) {
    const long long stride = (long long)gridDim.x * 256;
    for (long long i = (long long)blockIdx.x * 256 + threadIdx.x; i < n8;
         i += stride) {
        const float4 f0 = *(const float4*)(T + i * 8);
        const float4 f1 = *(const float4*)(T + i * 8 + 4);
        u16x8 o;
        o[0] = f2bf(f0.x); o[1] = f2bf(f0.y); o[2] = f2bf(f0.z); o[3] = f2bf(f0.w);
        o[4] = f2bf(f1.x); o[5] = f2bf(f1.y); o[6] = f2bf(f1.z); o[7] = f2bf(f1.w);
        *(u16x8*)(Tbf + i * 8) = o;
    }
}

// ---------------------------------------------------------------------------
// K1 fast path: scoresv from keys = tanh(Tbf@Wk+bk), scores = keys@Wq.
// 256 thr / 4 waves, wave tile 64x128 (acc[4][8]), BK=32, 16 iters.
// BOTH A (bf16 rows of Tbf) and B staged via global_load_lds: no VGPR
// round-trip, no f32->bf16 cvt, no ds_write in the hot loop -> ~9 async
// loads in flight per thread instead of ~1.4 (the round-2 latency ceiling).
// XOR granule swizzle via pre-swizzled GLOBAL source (glds dest linear),
// same involution on the ds_read side.
// ---------------------------------------------------------------------------
__global__ __launch_bounds__(256, 2)
void k_scores_fast(const ushort* __restrict__ Tbf, const ushort* __restrict__ Wkt,
                   const float* __restrict__ bk, const float* __restrict__ Wq,
                   float* __restrict__ scoresv) {
    __shared__ ushort Bs[2][512][32];                                  // 64 KB
    __shared__ union { ushort A[2][64][32]; float red[4][64][NHn]; } u;  // 8 KB

    const int mblk = blockIdx.x, nb = blockIdx.y;
    const int v0 = mblk * 64;
    const int tid = threadIdx.x, lane = tid & 63, w = tid >> 6;
    const int q = lane >> 4, c = lane & 15;
    const int gsw = (q ^ (c & 3)) * 8;   // swizzled granule offset for reads

    const ushort* Ab = Tbf + (size_t)nb * V1 * En;
    const ushort* Wn = Wkt + (size_t)nb * En * En;

    // A glds map: wave w stages tile rows w*16 .. w*16+15 (1 KB per call).
    // lane l -> LDS row w*16 + (l>>2), phys granule l&3; pre-swizzled source
    // granule (l&3) ^ ((l>>2)&3) so reads with gsw recover logical granules.
    const int ar  = w * 16 + (lane >> 2);
    const int ag  = (lane & 3) ^ ((lane >> 2) & 3);
    const int vrow = min(v0 + ar, V1 - 1);   // clamp: OOB rows read last row
    const ushort* agp = Ab + (size_t)vrow * En + ag * 8;

    f32x4 acc[4][8];
#pragma unroll
    for (int mt = 0; mt < 4; ++mt)
#pragma unroll
        for (int nt = 0; nt < 8; ++nt) acc[mt][nt] = (f32x4)0.0f;

    auto stageB = [&](int buf, int k0) {
#pragma unroll
        for (int j = 0; j < 8; ++j) {
            const int nrow = (w * 8 + j) * 16;
            const int r = nrow + (lane >> 2);
            const int gf = (lane & 3) ^ ((lane >> 2) & 3);  // pre-swizzled src
            const ushort* gp = Wn + (size_t)r * En + k0 + gf * 8;
            gl_lds16(gp, &Bs[buf][nrow][0]);
        }
    };
    auto stageA = [&](int buf, int k0) {
        gl_lds16(agp + k0, &u.A[buf][w * 16][0]);
    };

    // prologue
    stageA(0, 0);
    stageB(0, 0);
    __syncthreads();

    for (int it = 0; it < 16; ++it) {
        const int cur = it & 1, nxt = cur ^ 1;
        if (it < 15) {
            const int k0n = (it + 1) * 32;
            stageA(nxt, k0n);   // async into other buffer, no wait
            stageB(nxt, k0n);
        }
        bf16x8 aF[4], bF[8];
#pragma unroll
        for (int mt = 0; mt < 4; ++mt)
            aF[mt] = *(bf16x8*)&u.A[cur][mt * 16 + c][gsw];
#pragma unroll
        for (int nt = 0; nt < 8; ++nt)
            bF[nt] = *(bf16x8*)&Bs[cur][w * 128 + nt * 16 + c][gsw];
#pragma unroll
        for (int nt = 0; nt < 8; ++nt)
#pragma unroll
            for (int mt = 0; mt < 4; ++mt)
                acc[mt][nt] = __builtin_amdgcn_mfma_f32_16x16x32_bf16(
                    aF[mt], bF[nt], acc[mt][nt], 0, 0, 0);
        __syncthreads();  // drains glds for buf[nxt]; overlapped w/ MFMAs
    }

    // --- epilogue: keys = tanh(acc + bk[col]) in-register (fast tanh) ---
#pragma unroll
    for (int nt = 0; nt < 8; ++nt) {
        const int col = w * 128 + nt * 16 + c;
        const float bkv = bk[nb * En + col];
#pragma unroll
        for (int mt = 0; mt < 4; ++mt)
#pragma unroll
            for (int r = 0; r < 4; ++r)
                acc[mt][nt][r] = fast_tanh(acc[mt][nt][r] + bkv);
    }

    // --- scores: per head, dot over this wave's 128 cols; reduce 16 c-lanes
    //     via DPP xor1/xor2 (VALU) + shfl xor4/xor8.
    for (int h = 0; h < NHn; ++h) {
        float wqh[8];
#pragma unroll
        for (int nt = 0; nt < 8; ++nt) {
            const int col = w * 128 + nt * 16 + c;
            wqh[nt] = Wq[((size_t)nb * En + col) * NHn + h];
        }
        float p[4][4];
#pragma unroll
        for (int mt = 0; mt < 4; ++mt)
#pragma unroll
            for (int r = 0; r < 4; ++r) {
                float s = 0.f;
#pragma unroll
                for (int nt = 0; nt < 8; ++nt) s += acc[mt][nt][r] * wqh[nt];
                s += DPP_XOR1(s);
                s += DPP_XOR2(s);
                s += __shfl_xor(s, 4, 64);
                s += __shfl_xor(s, 8, 64);
                p[mt][r] = s;
            }
        if (c == h) {
#pragma unroll
            for (int mt = 0; mt < 4; ++mt)
#pragma unroll
                for (int r = 0; r < 4; ++r)
                    u.red[w][mt * 16 + q * 4 + r][h] = p[mt][r];
        }
    }
    __syncthreads();

    // --- cross-wave reduce, direct store (bq dropped: cancels in softmax) ---
    for (int idx = tid; idx < 64 * NHn; idx += 256) {
        const int row = idx >> 3, h = idx & 7;
        const int vr = v0 + row;
        if (vr < V1)
            scoresv[((size_t)nb * V1 + vr) * NHn + h] =
                u.red[0][row][h] + u.red[1][row][h] +
                u.red[2][row][h] + u.red[3][row][h];
    }
}

// ---------------------------------------------------------------------------
// K1 fallback (small workspace): round-2 structure, f32 A staging, no Tbf.
// ---------------------------------------------------------------------------
__global__ __launch_bounds__(256, 2)
void k_scores_slow(const float* __restrict__ T, const ushort* __restrict__ Wkt,
                   const float* __restrict__ bk, const float* __restrict__ Wq,
                   float* __restrict__ scoresv) {
    __shared__ ushort Bs[2][512][32];
    __shared__ union { ushort A[2][64][32]; float red[4][64][NHn]; } u;

    const int mblk = blockIdx.x, nb = blockIdx.y;
    const int v0 = mblk * 64;
    const int tid = threadIdx.x, lane = tid & 63, w = tid >> 6;
    const int q = lane >> 4, c = lane & 15;
    const int gsw = (q ^ (c & 3)) * 8;

    const float*  Tb = T + (size_t)nb * V1 * En;
    const ushort* Wn = Wkt + (size_t)nb * En * En;

    const int arow = tid >> 2, akq = tid & 3;
    const int aswz = (akq ^ (arow & 3)) * 8;
    const int vra = v0 + arow;
    const float* agp = Tb + (size_t)vra * En + akq * 8;

    f32x4 acc[4][8];
#pragma unroll
    for (int mt = 0; mt < 4; ++mt)
#pragma unroll
        for (int nt = 0; nt < 8; ++nt) acc[mt][nt] = (f32x4)0.0f;

    auto stageB = [&](int buf, int k0) {
#pragma unroll
        for (int j = 0; j < 8; ++j) {
            const int nrow = (w * 8 + j) * 16;
            const int r = nrow + (lane >> 2);
            const int gf = (lane & 3) ^ ((lane >> 2) & 3);
            const ushort* gp = Wn + (size_t)r * En + k0 + gf * 8;
            gl_lds16(gp, &Bs[buf][nrow][0]);
        }
    };
    auto loadA = [&](int k0, float4& f0, float4& f1) {
        if (vra < V1) {
            f0 = *(const float4*)(agp + k0);
            f1 = *(const float4*)(agp + k0 + 4);
        } else {
            f0 = make_float4(0.f, 0.f, 0.f, 0.f);
            f1 = f0;
        }
    };
    auto writeA = [&](int buf, float4 f0, float4 f1) {
        u16x8 o;
        o[0] = f2bf(f0.x); o[1] = f2bf(f0.y); o[2] = f2bf(f0.z); o[3] = f2bf(f0.w);
        o[4] = f2bf(f1.x); o[5] = f2bf(f1.y); o[6] = f2bf(f1.z); o[7] = f2bf(f1.w);
        *(u16x8*)&u.A[buf][arow][aswz] = o;
    };

    stageB(0, 0);
    {
        float4 f0, f1;
        loadA(0, f0, f1);
        writeA(0, f0, f1);
    }
    __syncthreads();

    for (int it = 0; it < 16; ++it) {
        const int cur = it & 1, nxt = cur ^ 1;
        const int k0n = (it + 1) * 32;
        float4 p0, p1;
        if (it < 15) {
            stageB(nxt, k0n);
            loadA(k0n, p0, p1);
        }
        bf16x8 aF[4], bF[8];
#pragma unroll
        for (int mt = 0; mt < 4; ++mt)
            aF[mt] = *(bf16x8*)&u.A[cur][mt * 16 + c][gsw];
#pragma unroll
        for (int nt = 0; nt < 8; ++nt)
            bF[nt] = *(bf16x8*)&Bs[cur][w * 128 + nt * 16 + c][gsw];
#pragma unroll
        for (int nt = 0; nt < 8; ++nt)
#pragma unroll
            for (int mt = 0; mt < 4; ++mt)
                acc[mt][nt] = __builtin_amdgcn_mfma_f32_16x16x32_bf16(
                    aF[mt], bF[nt], acc[mt][nt], 0, 0, 0);
        if (it < 15) writeA(nxt, p0, p1);
        __syncthreads();
    }

#pragma unroll
    for (int nt = 0; nt < 8; ++nt) {
        const int col = w * 128 + nt * 16 + c;
        const float bkv = bk[nb * En + col];
#pragma unroll
        for (int mt = 0; mt < 4; ++mt)
#pragma unroll
            for (int r = 0; r < 4; ++r)
                acc[mt][nt][r] = fast_tanh(acc[mt][nt][r] + bkv);
    }

    for (int h = 0; h < NHn; ++h) {
        float wqh[8];
#pragma unroll
        for (int nt = 0; nt < 8; ++nt) {
            const int col = w * 128 + nt * 16 + c;
            wqh[nt] = Wq[((size_t)nb * En + col) * NHn + h];
        }
        float p[4][4];
#pragma unroll
        for (int mt = 0; mt < 4; ++mt)
#pragma unroll
            for (int r = 0; r < 4; ++r) {
                float s = 0.f;
#pragma unroll
                for (int nt = 0; nt < 8; ++nt) s += acc[mt][nt][r] * wqh[nt];
                s += DPP_XOR1(s);
                s += DPP_XOR2(s);
                s += __shfl_xor(s, 4, 64);
                s += __shfl_xor(s, 8, 64);
                p[mt][r] = s;
            }
        if (c == h) {
#pragma unroll
            for (int mt = 0; mt < 4; ++mt)
#pragma unroll
                for (int r = 0; r < 4; ++r)
                    u.red[w][mt * 16 + q * 4 + r][h] = p[mt][r];
        }
    }
    __syncthreads();

    for (int idx = tid; idx < 64 * NHn; idx += 256) {
        const int row = idx >> 3, h = idx & 7;
        const int vr = v0 + row;
        if (vr < V1)
            scoresv[((size_t)nb * V1 + vr) * NHn + h] =
                u.red[0][row][h] + u.red[1][row][h] +
                u.red[2][row][h] + u.red[3][row][h];
    }
}

// ---------------------------------------------------------------------------
// K2: masked softmax over genes, per (nb, b); writes attn weights (head-sum).
// ---------------------------------------------------------------------------
__global__ __launch_bounds__(256)
void k_softmax(const int* __restrict__ sga, const float* __restrict__ scoresv,
               float* __restrict__ attn_out) {
    const int b  = blockIdx.x;
    const int nb = blockIdx.y;
    const int tid = threadIdx.x;
    const int lane = tid & 63;
    const int wid  = tid >> 6;
    __shared__ float red[4 * NHn];

    float sc[4][NHn];
    int ivals[4];
#pragma unroll
    for (int s = 0; s < 4; ++s) {
        const int i = tid + s * 256;
        ivals[s] = i;
        if (i < In) {
            const int v = sga[b * In + i];
            const float4 s0 = *(const float4*)(scoresv + ((size_t)nb * V1 + v) * NHn);
            const float4 s1 = *(const float4*)(scoresv + ((size_t)nb * V1 + v) * NHn + 4);
            sc[s][0] = s0.x; sc[s][1] = s0.y; sc[s][2] = s0.z; sc[s][3] = s0.w;
            sc[s][4] = s1.x; sc[s][5] = s1.y; sc[s][6] = s1.z; sc[s][7] = s1.w;
            if (v == 0) {
#pragma unroll
                for (int n = 0; n < NHn; ++n) sc[s][n] = -1e9f;
            }
        } else {
#pragma unroll
            for (int n = 0; n < NHn; ++n) sc[s][n] = -3.0e38f;
        }
    }

    float lm[NHn];
#pragma unroll
    for (int n = 0; n < NHn; ++n)
        lm[n] = fmaxf(fmaxf(sc[0][n], sc[1][n]), fmaxf(sc[2][n], sc[3][n]));
#pragma unroll
    for (int m = 1; m < 64; m <<= 1) {
#pragma unroll
        for (int n = 0; n < NHn; ++n) lm[n] = fmaxf(lm[n], __shfl_xor(lm[n], m, 64));
    }
    if (lane == 0) {
#pragma unroll
        for (int n = 0; n < NHn; ++n) red[wid * NHn + n] = lm[n];
    }
    __syncthreads();
    float M[NHn];
#pragma unroll
    for (int n = 0; n < NHn; ++n)
        M[n] = fmaxf(fmaxf(red[n], red[NHn + n]), fmaxf(red[2 * NHn + n], red[3 * NHn + n]));
    __syncthreads();

    float ls[NHn];
#pragma unroll
    for (int n = 0; n < NHn; ++n) ls[n] = 0.f;
#pragma unroll
    for (int s = 0; s < 4; ++s) {
#pragma unroll
        for (int n = 0; n < NHn; ++n) {
            sc[s][n] = expf(sc[s][n] - M[n]);
            ls[n] += sc[s][n];
        }
    }
#pragma unroll
    for (int m = 1; m < 64; m <<= 1) {
#pragma unroll
        for (int n = 0; n < NHn; ++n) ls[n] += __shfl_xor(ls[n], m, 64);
    }
    if (lane == 0) {
#pragma unroll
        for (int n = 0; n < NHn; ++n) red[wid * NHn + n] = ls[n];
    }
    __syncthreads();
    float inv[NHn];
#pragma unroll
    for (int n = 0; n < NHn; ++n) {
        const float S = red[n] + red[NHn + n] + red[2 * NHn + n] + red[3 * NHn + n];
        inv[n] = 1.0f / S;
    }

#pragma unroll
    for (int s = 0; s < 4; ++s) {
        if (ivals[s] < In) {
            float w = 0.f;
#pragma unroll
            for (int n = 0; n < NHn; ++n) w += sc[s][n] * inv[n];
            attn_out[((size_t)nb * Bn + b) * In + ivals[s]] = w;
        }
    }
}

// ---------------------------------------------------------------------------
// K3: emb[nb][b][e] = sum_i w[nb,b,i] * T[nb][sga[b,i]][e]
// 512 threads = 8 waves x 100 genes; LDS partial reduce.
// TBF variant gathers bf16 rows (half the L3 traffic); unroll 10 keeps 10
// independent 1KB row-gathers in flight per wave.
// ---------------------------------------------------------------------------
template <bool TBF>
__global__ __launch_bounds__(512)
void k_emb(const int* __restrict__ sga, const float* __restrict__ attn,
           const float* __restrict__ T, const ushort* __restrict__ Tbf,
           float* __restrict__ emb) {
    const int b  = blockIdx.x;
    const int nb = blockIdx.y;
    __shared__ int   sv[In];
    __shared__ float sw[In];
    __shared__ float pa[8][En];  // 16 KB
    for (int idx = threadIdx.x; idx < In; idx += 512) {
        sv[idx] = sga[b * In + idx];
        sw[idx] = attn[((size_t)nb * Bn + b) * In + idx];
    }
    __syncthreads();
    const int wave = threadIdx.x >> 6, lane = threadIdx.x & 63;
    float a[8];
#pragma unroll
    for (int j = 0; j < 8; ++j) a[j] = 0.f;

    if (TBF) {
        const ushort* Tb = Tbf + (size_t)nb * V1 * En;
#pragma unroll 10
        for (int g = 0; g < 100; ++g) {
            const int i = wave * 100 + g;
            const int v = sv[i];
            const float w = sw[i];
            const u16x8 t = *(const u16x8*)(Tb + (size_t)v * En + lane * 8);
#pragma unroll
            for (int j = 0; j < 8; ++j) a[j] += w * bf2f(t[j]);
        }
    } else {
        const float* Tb = T + (size_t)nb * V1 * En;
#pragma unroll 10
        for (int g = 0; g < 100; ++g) {
            const int i = wave * 100 + g;
            const int v = sv[i];
            const float w = sw[i];
            const float4* p = (const float4*)(Tb + (size_t)v * En) + lane * 2;
            const float4 t0 = p[0], t1 = p[1];
            a[0] += w * t0.x; a[1] += w * t0.y; a[2] += w * t0.z; a[3] += w * t0.w;
            a[4] += w * t1.x; a[5] += w * t1.y; a[6] += w * t1.z; a[7] += w * t1.w;
        }
    }
#pragma unroll
    for (int j = 0; j < 8; ++j) pa[wave][lane * 8 + j] = a[j];
    __syncthreads();
    const int t = threadIdx.x;
    float s = 0.f;
#pragma unroll
    for (int wv = 0; wv < 8; ++wv) s += pa[wv][t];
    emb[((size_t)nb * Bn + b) * En + t] = s;
}

// ---------------------------------------------------------------------------
// K4a: curr0 = relu(emb0 + can_emb[can]); hiddens[0] = curr0
// ---------------------------------------------------------------------------
__global__ __launch_bounds__(256)
void k_step0(const float* __restrict__ emb0, const int* __restrict__ can,
             const float* __restrict__ can_emb, float* __restrict__ cur,
             float* __restrict__ hid) {
    const int b = blockIdx.x;
    const int e0 = threadIdx.x * 2;
    const int c = can[b];
    float2 v = *(const float2*)(emb0 + (size_t)b * En + e0);
    const float2 ce = *(const float2*)(can_emb + (size_t)c * En + e0);
    v.x = fmaxf(v.x + ce.x, 0.f);
    v.y = fmaxf(v.y + ce.y, 0.f);
    *(float2*)(cur + (size_t)b * En + e0) = v;
    *(float2*)(hid + (size_t)b * En + e0) = v;
}

// ---------------------------------------------------------------------------
// K4b: curr = act(emb_i + prev @ Wh), K-split over 2 half-ranges,
// grid (b, 4 col-chunks) = 512 blocks.  act: 0=relu, 1=sigmoid
// ---------------------------------------------------------------------------
__global__ __launch_bounds__(256)
void k_step(const float* __restrict__ embi, const float* __restrict__ prev,
            const float* __restrict__ Whi, float* __restrict__ cur,
            float* __restrict__ hid, const int sig) {
    const int b = blockIdx.x, cc = blockIdx.y;
    __shared__ float pr[En];
    __shared__ float part[2][128];
    pr[threadIdx.x]       = prev[(size_t)b * En + threadIdx.x];
    pr[threadIdx.x + 256] = prev[(size_t)b * En + threadIdx.x + 256];
    __syncthreads();
    const int col = cc * 128 + (threadIdx.x & 127);
    const int kh  = threadIdx.x >> 7;
    float s = 0.f;
    const float* Wp = Whi + (size_t)(kh * 256) * En + col;
#pragma unroll 8
    for (int k = 0; k < 256; ++k) s += pr[kh * 256 + k] * Wp[(size_t)k * En];
    part[kh][threadIdx.x & 127] = s;
    __syncthreads();
    if (threadIdx.x < 128) {
        float a = part[0][threadIdx.x] + part[1][threadIdx.x] +
                  embi[(size_t)b * En + col];
        if (sig) a = 1.0f / (1.0f + expf(-a));
        else     a = fmaxf(a, 0.f);
        cur[(size_t)b * En + col] = a;
        hid[(size_t)b * En + col] = a;
    }
}

// ---------------------------------------------------------------------------
// K5: preds = curr3 @ Wfinal   [128,512]@[512,5000]
// ---------------------------------------------------------------------------
__global__ __launch_bounds__(256, 2)
void k_preds(const float* __restrict__ cur, const float* __restrict__ Wf,
             float* __restrict__ preds) {
    __shared__ float cs[32 * En];  // 64 KB
    const int nt = blockIdx.x;
    const int bt = blockIdx.y;
    for (int idx = threadIdx.x; idx < 32 * 128; idx += 256) {
        const int row = idx >> 7;
        const int c4  = (idx & 127) << 2;
        *(float4*)(cs + row * En + c4) =
            *(const float4*)(cur + (size_t)(bt * 32 + row) * En + c4);
    }
    __syncthreads();
    const int lane = threadIdx.x & 63;
    const int rgrp = threadIdx.x >> 6;
    const int col = nt * 64 + lane;
    float acc[8];
#pragma unroll
    for (int j = 0; j < 8; ++j) acc[j] = 0.f;
    const bool ok = (col < OUTn);
    for (int k = 0; k < En; k += 4) {
        float w0 = 0.f, w1 = 0.f, w2 = 0.f, w3 = 0.f;
        if (ok) {
            w0 = Wf[(size_t)(k + 0) * OUTn + col];
            w1 = Wf[(size_t)(k + 1) * OUTn + col];
            w2 = Wf[(size_t)(k + 2) * OUTn + col];
            w3 = Wf[(size_t)(k + 3) * OUTn + col];
        }
#pragma unroll
        for (int j = 0; j < 8; ++j) {
            const float4 cv = *(const float4*)(cs + (rgrp * 8 + j) * En + k);
            acc[j] += cv.x * w0 + cv.y * w1 + cv.z * w2 + cv.w * w3;
        }
    }
    if (ok) {
#pragma unroll
        for (int j = 0; j < 8; ++j)
            preds[(size_t)(bt * 32 + rgrp * 8 + j) * OUTn + col] = acc[j];
    }
}

// ---------------------------------------------------------------------------
extern "C" void kernel_launch(void* const* d_in, const int* in_sizes, int n_in,
                              void* d_out, int out_size, void* d_ws, size_t ws_size,
                              hipStream_t stream) {
    const int*   sga     = (const int*)d_in[0];
    const int*   can     = (const int*)d_in[1];
    const float* T       = (const float*)d_in[2];
    const float* Wk      = (const float*)d_in[3];
    const float* bk      = (const float*)d_in[4];
    const float* Wq      = (const float*)d_in[5];
    // d_in[6] = bq: unused — constant over softmax axis, cancels exactly
    const float* can_emb = (const float*)d_in[7];
    const float* Wh      = (const float*)d_in[8];
    const float* Wf      = (const float*)d_in[9];

    float* out = (float*)d_out;
    float* ws  = (float*)d_ws;

    // workspace layout (floats; all 16B-aligned)
    float* scoresv = ws;                                // NB*V1*NH   = 608032
    float* embw    = scoresv + (size_t)NBn * V1 * NHn;  // NB*B*E     = 262144
    float* cur0    = embw + (size_t)NBn * Bn * En;      // B*E
    float* cur1    = cur0 + (size_t)Bn * En;            // B*E
    ushort* Wkt    = (ushort*)(cur1 + (size_t)Bn * En); // NB*E*E bf16 = 2 MB
    ushort* Tbf    = Wkt + (size_t)NBn * En * En;       // NB*V1*E bf16 = 78 MB
    const size_t need_full =
        (size_t)(scoresv - ws) * 4 +
        ((size_t)NBn * V1 * NHn + (size_t)NBn * Bn * En + 2 * (size_t)Bn * En) * 4 +
        (size_t)NBn * En * En * 2 + (size_t)NBn * V1 * En * 2;
    const bool useTbf = (ws_size >= need_full);

    float* preds_out = out;
    float* attn_out  = out + OFF_ATTN;
    float* hid_out   = out + OFF_HID;

    // K0: Wk -> bf16 transposed [nb][n][k]
    k_prep<<<dim3(8, 8, NBn), 256, 0, stream>>>(Wk, Wkt);
    if (useTbf) {
        // K0b: T -> bf16 (streaming, full BW)
        const long long n8 = (long long)NBn * V1 * En / 8;
        k_cvt<<<2048, 256, 0, stream>>>(T, Tbf, n8);
        // K1: all-glds keys-GEMM + scores epilogue
        k_scores_fast<<<dim3((V1 + 63) / 64, NBn), 256, 0, stream>>>(
            Tbf, Wkt, bk, Wq, scoresv);
    } else {
        k_scores_slow<<<dim3((V1 + 63) / 64, NBn), 256, 0, stream>>>(
            T, Wkt, bk, Wq, scoresv);
    }
    // K2: softmax + head-sum -> attns (directly to d_out)
    k_softmax<<<dim3(Bn, NBn), 256, 0, stream>>>(sga, scoresv, attn_out);
    // K3: weighted embedding sums (bf16 gather if Tbf available)
    if (useTbf)
        k_emb<true><<<dim3(Bn, NBn), 512, 0, stream>>>(sga, attn_out, T, Tbf, embw);
    else
        k_emb<false><<<dim3(Bn, NBn), 512, 0, stream>>>(sga, attn_out, T, Tbf, embw);
    // K4: residual chain
    k_step0<<<Bn, 256, 0, stream>>>(embw, can, can_emb, cur0, hid_out);
    k_step<<<dim3(Bn, 4), 256, 0, stream>>>(embw + 1 * Bn * En, cur0,
                                            Wh + 0 * En * En, cur1,
                                            hid_out + 1 * (size_t)Bn * En, 0);
    k_step<<<dim3(Bn, 4), 256, 0, stream>>>(embw + 2 * Bn * En, cur1,
                                            Wh + 1 * En * En, cur0,
                                            hid_out + 2 * (size_t)Bn * En, 0);
    k_step<<<dim3(Bn, 4), 256, 0, stream>>>(embw + 3 * Bn * En, cur0,
                                            Wh + 2 * En * En, cur1,
                                            hid_out + 3 * (size_t)Bn * En, 1);
    // K5: final projection
    k_preds<<<dim3((OUTn + 63) / 64, Bn / 32), 256, 0, stream>>>(cur1, Wf, preds_out);
}

// Round 4
// 533.087 us; speedup vs baseline: 1.1769x; 1.0162x over previous
//
#include <hip/hip_runtime.h>
#include <hip/hip_bf16.h>

// Problem constants
constexpr int Bn   = 128;    // batch
constexpr int In   = 800;    // genes per case
constexpr int En   = 512;    // embed dim
constexpr int V1   = 19001;  // vocab + padding row
constexpr int NHn  = 8;      // heads
constexpr int NBn  = 4;      // attention blocks
constexpr int OUTn = 5000;   // output genes

// d_out layout (floats): preds [B,OUT] | attns [NB,B,I] | hiddens [NB,B,E]
constexpr int OFF_ATTN = Bn * OUTn;                 // 640000
constexpr int OFF_HID  = OFF_ATTN + NBn * Bn * In;  // 1049600

typedef __attribute__((ext_vector_type(8))) short bf16x8;
typedef __attribute__((ext_vector_type(8))) unsigned short u16x8;
typedef __attribute__((ext_vector_type(4))) float f32x4;

__device__ inline ushort f2bf(float x) {
    __hip_bfloat16 h = __float2bfloat16(x);
    return *reinterpret_cast<ushort*>(&h);
}
__device__ inline float bf2f(ushort u) {
    return __uint_as_float(((unsigned)u) << 16);
}
__device__ inline void gl_lds16(const ushort* g, ushort* l) {
    __builtin_amdgcn_global_load_lds(
        (const __attribute__((address_space(1))) void*)g,
        (__attribute__((address_space(3))) void*)l, 16, 0, 0);
}

// fast tanh: 1 - 2/(e^{2x}+1) with HW rcp (no IEEE divide; rel err ~1e-7,
// negligible vs bf16 inputs).  Saturates to +-1, no NaN for large |x|.
__device__ inline float fast_tanh(float x) {
    const float e = __expf(2.0f * x);
    return 1.0f - 2.0f * __builtin_amdgcn_rcpf(e + 1.0f);
}

// DPP quad-perm xor-1 / xor-2 (VALU lane exchange, keeps LDS pipe free)
#define DPP_XOR1(x) __int_as_float(__builtin_amdgcn_update_dpp( \
    0, __float_as_int(x), 0xB1, 0xF, 0xF, false))
#define DPP_XOR2(x) __int_as_float(__builtin_amdgcn_update_dpp( \
    0, __float_as_int(x), 0x4E, 0xF, 0xF, false))

// ---------------------------------------------------------------------------
// K0: Wkt K-panel tiled layout:
//   Wkt[nb][kt][n][ks]  (kt = k>>5, ks = k&31), panel = 512 x 32 contiguous.
// So each K-step's B tile is one contiguous 32 KB block -> glds staging reads
// 1 KB fully-contiguous per instruction (8 full 128B lines, no half-line
// requests).  Transposed+bf16 via LDS tile as before.
// ---------------------------------------------------------------------------
__global__ __launch_bounds__(256)
void k_prep(const float* __restrict__ Wk, ushort* __restrict__ Wkt) {
    __shared__ float ts[64][65];
    const int n0 = blockIdx.x * 64, k0 = blockIdx.y * 64, nb = blockIdx.z;
    const int t = threadIdx.x;
    {
        const int kr = t >> 2, nc = (t & 3) * 16;
        const float* p = Wk + (((size_t)nb * En) + (k0 + kr)) * En + n0 + nc;
#pragma unroll
        for (int j = 0; j < 4; ++j) {
            const float4 v = *(const float4*)(p + j * 4);
            ts[kr][nc + j * 4 + 0] = v.x; ts[kr][nc + j * 4 + 1] = v.y;
            ts[kr][nc + j * 4 + 2] = v.z; ts[kr][nc + j * 4 + 3] = v.w;
        }
    }
    __syncthreads();
    {
        const int nr = t >> 2, kc = (t & 3) * 16;
        const int n = n0 + nr;
#pragma unroll
        for (int j = 0; j < 4; ++j) {
            const int k = k0 + kc + j * 4;
            const int kt = k >> 5, ks = k & 31;
            ushort* d = Wkt + (size_t)nb * En * En + (size_t)kt * En * 32 +
                        (size_t)n * 32 + ks;
            ushort4 o;
            o.x = f2bf(ts[kc + j * 4 + 0][nr]); o.y = f2bf(ts[kc + j * 4 + 1][nr]);
            o.z = f2bf(ts[kc + j * 4 + 2][nr]); o.w = f2bf(ts[kc + j * 4 + 3][nr]);
            *(ushort4*)d = o;
        }
    }
}

// ---------------------------------------------------------------------------
// K0q: Wqt[nb][h][n] = Wq[nb][n][h]  (f32) so the epilogue's per-head weight
// loads are coalesced (consecutive c-lanes -> consecutive addresses).
// ---------------------------------------------------------------------------
__global__ __launch_bounds__(256)
void k_prepq(const float* __restrict__ Wq, float* __restrict__ Wqt) {
    const int nb = blockIdx.x;
    for (int idx = threadIdx.x; idx < En * NHn; idx += 256) {
        const int h = idx >> 9, n = idx & (En - 1);
        Wqt[(size_t)nb * NHn * En + idx] = Wq[((size_t)nb * En + n) * NHn + h];
    }
}

// ---------------------------------------------------------------------------
// K0b: Tbf = bf16(T), pure streaming at HBM BW.
// ---------------------------------------------------------------------------
__global__ __launch_bounds__(256)
void k_cvt(const float* __restrict__ T, ushort* __restrict__ Tbf,
           const long long n8) {
    const long long stride = (long long)gridDim.x * 256;
    for (long long i = (long long)blockIdx.x * 256 + threadIdx.x; i < n8;
         i += stride) {
        const float4 f0 = *(const float4*)(T + i * 8);
        const float4 f1 = *(const float4*)(T + i * 8 + 4);
        u16x8 o;
        o[0] = f2bf(f0.x); o[1] = f2bf(f0.y); o[2] = f2bf(f0.z); o[3] = f2bf(f0.w);
        o[4] = f2bf(f1.x); o[5] = f2bf(f1.y); o[6] = f2bf(f1.z); o[7] = f2bf(f1.w);
        *(u16x8*)(Tbf + i * 8) = o;
    }
}

// ---------------------------------------------------------------------------
// K1 fast path: scoresv from keys = tanh(Tbf@Wk+bk), scores = keys@Wq.
// 256 thr / 4 waves, wave tile 64x128 (acc[4][8]), BK=32, 16 iters,
// A+B both via global_load_lds (B from contiguous K-panels).
// Swizzle: row r stores logical granule g at physical g ^ ((r>>2)&3);
// reader lane (q,c) reads physical q ^ (c>>2) -> within a 16-lane phase
// (fixed q) banks spread 2-way = conflict-free (m136).
// ---------------------------------------------------------------------------
__global__ __launch_bounds__(256, 2)
void k_scores_fast(const ushort* __restrict__ Tbf, const ushort* __restrict__ Wkt,
                   const float* __restrict__ bk, const float* __restrict__ Wqt,
                   float* __restrict__ scoresv) {
    __shared__ ushort Bs[2][512][32];                                  // 64 KB
    __shared__ union { ushort A[2][64][32]; float red[4][64][NHn]; } u;  // 8 KB

    const int mblk = blockIdx.x, nb = blockIdx.y;
    const int v0 = mblk * 64;
    const int tid = threadIdx.x, lane = tid & 63, w = tid >> 6;
    const int q = lane >> 4, c = lane & 15;
    const int gsw = (q ^ (c >> 2)) * 8;   // physical granule for reads

    const ushort* Ab = Tbf + (size_t)nb * V1 * En;
    const ushort* Wn = Wkt + (size_t)nb * En * En;   // K-panel tiled

    // staging source granule: physical (l&3) at row ..+(l>>2) needs logical
    // (l&3) ^ ((row>>2)&3) = (l&3) ^ ((l>>4)&3)
    const int sg = (lane & 3) ^ ((lane >> 4) & 3);

    // A glds map: wave w stages rows w*16 .. w*16+15 (1 KB per call).
    const int ar   = w * 16 + (lane >> 2);
    const int vrow = min(v0 + ar, V1 - 1);   // clamp: OOB rows read last row
    const ushort* agp = Ab + (size_t)vrow * En + sg * 8;

    f32x4 acc[4][8];
#pragma unroll
    for (int mt = 0; mt < 4; ++mt)
#pragma unroll
        for (int nt = 0; nt < 8; ++nt) acc[mt][nt] = (f32x4)0.0f;

    auto stageB = [&](int buf, int kt) {
        const ushort* Wp = Wn + (size_t)kt * En * 32;
#pragma unroll
        for (int j = 0; j < 8; ++j) {
            const int nrow = (w * 8 + j) * 16;
            // contiguous 1 KB: rows nrow..nrow+15 of the K-panel
            const ushort* gp = Wp + (size_t)(nrow + (lane >> 2)) * 32 + sg * 8;
            gl_lds16(gp, &Bs[buf][nrow][0]);
        }
    };
    auto stageA = [&](int buf, int k0) {
        gl_lds16(agp + k0, &u.A[buf][w * 16][0]);
    };

    // prologue
    stageA(0, 0);
    stageB(0, 0);
    __syncthreads();

    for (int it = 0; it < 16; ++it) {
        const int cur = it & 1, nxt = cur ^ 1;
        if (it < 15) {
            stageA(nxt, (it + 1) * 32);   // async into other buffer, no wait
            stageB(nxt, it + 1);
        }
        bf16x8 aF[4], bF[8];
#pragma unroll
        for (int mt = 0; mt < 4; ++mt)
            aF[mt] = *(bf16x8*)&u.A[cur][mt * 16 + c][gsw];
#pragma unroll
        for (int nt = 0; nt < 8; ++nt)
            bF[nt] = *(bf16x8*)&Bs[cur][w * 128 + nt * 16 + c][gsw];
#pragma unroll
        for (int nt = 0; nt < 8; ++nt)
#pragma unroll
            for (int mt = 0; mt < 4; ++mt)
                acc[mt][nt] = __builtin_amdgcn_mfma_f32_16x16x32_bf16(
                    aF[mt], bF[nt], acc[mt][nt], 0, 0, 0);
        __syncthreads();  // drains glds for buf[nxt]; overlapped w/ MFMAs
    }

    // --- epilogue: keys = tanh(acc + bk[col]) in-register (rcp tanh) ---
#pragma unroll
    for (int nt = 0; nt < 8; ++nt) {
        const int col = w * 128 + nt * 16 + c;
        const float bkv = bk[nb * En + col];
#pragma unroll
        for (int mt = 0; mt < 4; ++mt)
#pragma unroll
            for (int r = 0; r < 4; ++r)
                acc[mt][nt][r] = fast_tanh(acc[mt][nt][r] + bkv);
    }

    // --- scores: per head, dot over this wave's 128 cols; reduce 16 c-lanes
    //     via DPP xor1/xor2 (VALU) + shfl xor4/xor8.  Wqt loads coalesced.
    const float* Wqn = Wqt + (size_t)nb * NHn * En;
    for (int h = 0; h < NHn; ++h) {
        float wqh[8];
#pragma unroll
        for (int nt = 0; nt < 8; ++nt) {
            const int col = w * 128 + nt * 16 + c;
            wqh[nt] = Wqn[h * En + col];
        }
        float p[4][4];
#pragma unroll
        for (int mt = 0; mt < 4; ++mt)
#pragma unroll
            for (int r = 0; r < 4; ++r) {
                float s = 0.f;
#pragma unroll
                for (int nt = 0; nt < 8; ++nt) s += acc[mt][nt][r] * wqh[nt];
                s += DPP_XOR1(s);
                s += DPP_XOR2(s);
                s += __shfl_xor(s, 4, 64);
                s += __shfl_xor(s, 8, 64);
                p[mt][r] = s;
            }
        if (c == h) {
#pragma unroll
            for (int mt = 0; mt < 4; ++mt)
#pragma unroll
                for (int r = 0; r < 4; ++r)
                    u.red[w][mt * 16 + q * 4 + r][h] = p[mt][r];
        }
    }
    __syncthreads();

    // --- cross-wave reduce, direct store (bq dropped: cancels in softmax) ---
    for (int idx = tid; idx < 64 * NHn; idx += 256) {
        const int row = idx >> 3, h = idx & 7;
        const int vr = v0 + row;
        if (vr < V1)
            scoresv[((size_t)nb * V1 + vr) * NHn + h] =
                u.red[0][row][h] + u.red[1][row][h] +
                u.red[2][row][h] + u.red[3][row][h];
    }
}

// ---------------------------------------------------------------------------
// K1 fallback (small workspace): f32 A staging, no Tbf.  Uses tiled Wkt and
// the same swizzle involution.
// ---------------------------------------------------------------------------
__global__ __launch_bounds__(256, 2)
void k_scores_slow(const float* __restrict__ T, const ushort* __restrict__ Wkt,
                   const float* __restrict__ bk, const float* __restrict__ Wq,
                   float* __restrict__ scoresv) {
    __shared__ ushort Bs[2][512][32];
    __shared__ union { ushort A[2][64][32]; float red[4][64][NHn]; } u;

    const int mblk = blockIdx.x, nb = blockIdx.y;
    const int v0 = mblk * 64;
    const int tid = threadIdx.x, lane = tid & 63, w = tid >> 6;
    const int q = lane >> 4, c = lane & 15;
    const int gsw = (q ^ (c >> 2)) * 8;
    const int sg = (lane & 3) ^ ((lane >> 4) & 3);

    const float*  Tb = T + (size_t)nb * V1 * En;
    const ushort* Wn = Wkt + (size_t)nb * En * En;

    const int arow = tid >> 2, akq = tid & 3;
    const int aswz = (akq ^ ((arow >> 2) & 3)) * 8;
    const int vra = v0 + arow;
    const float* agp = Tb + (size_t)vra * En + akq * 8;

    f32x4 acc[4][8];
#pragma unroll
    for (int mt = 0; mt < 4; ++mt)
#pragma unroll
        for (int nt = 0; nt < 8; ++nt) acc[mt][nt] = (f32x4)0.0f;

    auto stageB = [&](int buf, int kt) {
        const ushort* Wp = Wn + (size_t)kt * En * 32;
#pragma unroll
        for (int j = 0; j < 8; ++j) {
            const int nrow = (w * 8 + j) * 16;
            const ushort* gp = Wp + (size_t)(nrow + (lane >> 2)) * 32 + sg * 8;
            gl_lds16(gp, &Bs[buf][nrow][0]);
        }
    };
    auto loadA = [&](int k0, float4& f0, float4& f1) {
        if (vra < V1) {
            f0 = *(const float4*)(agp + k0);
            f1 = *(const float4*)(agp + k0 + 4);
        } else {
            f0 = make_float4(0.f, 0.f, 0.f, 0.f);
            f1 = f0;
        }
    };
    auto writeA = [&](int buf, float4 f0, float4 f1) {
        u16x8 o;
        o[0] = f2bf(f0.x); o[1] = f2bf(f0.y); o[2] = f2bf(f0.z); o[3] = f2bf(f0.w);
        o[4] = f2bf(f1.x); o[5] = f2bf(f1.y); o[6] = f2bf(f1.z); o[7] = f2bf(f1.w);
        *(u16x8*)&u.A[buf][arow][aswz] = o;
    };

    stageB(0, 0);
    {
        float4 f0, f1;
        loadA(0, f0, f1);
        writeA(0, f0, f1);
    }
    __syncthreads();

    for (int it = 0; it < 16; ++it) {
        const int cur = it & 1, nxt = cur ^ 1;
        const int k0n = (it + 1) * 32;
        float4 p0, p1;
        if (it < 15) {
            stageB(nxt, it + 1);
            loadA(k0n, p0, p1);
        }
        bf16x8 aF[4], bF[8];
#pragma unroll
        for (int mt = 0; mt < 4; ++mt)
            aF[mt] = *(bf16x8*)&u.A[cur][mt * 16 + c][gsw];
#pragma unroll
        for (int nt = 0; nt < 8; ++nt)
            bF[nt] = *(bf16x8*)&Bs[cur][w * 128 + nt * 16 + c][gsw];
#pragma unroll
        for (int nt = 0; nt < 8; ++nt)
#pragma unroll
            for (int mt = 0; mt < 4; ++mt)
                acc[mt][nt] = __builtin_amdgcn_mfma_f32_16x16x32_bf16(
                    aF[mt], bF[nt], acc[mt][nt], 0, 0, 0);
        if (it < 15) writeA(nxt, p0, p1);
        __syncthreads();
    }

#pragma unroll
    for (int nt = 0; nt < 8; ++nt) {
        const int col = w * 128 + nt * 16 + c;
        const float bkv = bk[nb * En + col];
#pragma unroll
        for (int mt = 0; mt < 4; ++mt)
#pragma unroll
            for (int r = 0; r < 4; ++r)
                acc[mt][nt][r] = fast_tanh(acc[mt][nt][r] + bkv);
    }

    for (int h = 0; h < NHn; ++h) {
        float wqh[8];
#pragma unroll
        for (int nt = 0; nt < 8; ++nt) {
            const int col = w * 128 + nt * 16 + c;
            wqh[nt] = Wq[((size_t)nb * En + col) * NHn + h];
        }
        float p[4][4];
#pragma unroll
        for (int mt = 0; mt < 4; ++mt)
#pragma unroll
            for (int r = 0; r < 4; ++r) {
                float s = 0.f;
#pragma unroll
                for (int nt = 0; nt < 8; ++nt) s += acc[mt][nt][r] * wqh[nt];
                s += DPP_XOR1(s);
                s += DPP_XOR2(s);
                s += __shfl_xor(s, 4, 64);
                s += __shfl_xor(s, 8, 64);
                p[mt][r] = s;
            }
        if (c == h) {
#pragma unroll
            for (int mt = 0; mt < 4; ++mt)
#pragma unroll
                for (int r = 0; r < 4; ++r)
                    u.red[w][mt * 16 + q * 4 + r][h] = p[mt][r];
        }
    }
    __syncthreads();

    for (int idx = tid; idx < 64 * NHn; idx += 256) {
        const int row = idx >> 3, h = idx & 7;
        const int vr = v0 + row;
        if (vr < V1)
            scoresv[((size_t)nb * V1 + vr) * NHn + h] =
                u.red[0][row][h] + u.red[1][row][h] +
                u.red[2][row][h] + u.red[3][row][h];
    }
}

// ---------------------------------------------------------------------------
// K2: masked softmax over genes, per (nb, b); writes attn weights (head-sum).
// ---------------------------------------------------------------------------
__global__ __launch_bounds__(256)
void k_softmax(const int* __restrict__ sga, const float* __restrict__ scoresv,
               float* __restrict__ attn_out) {
    const int b  = blockIdx.x;
    const int nb = blockIdx.y;
    const int tid = threadIdx.x;
    const int lane = tid & 63;
    const int wid  = tid >> 6;
    __shared__ float red[4 * NHn];

    float sc[4][NHn];
    int ivals[4];
#pragma unroll
    for (int s = 0; s < 4; ++s) {
        const int i = tid + s * 256;
        ivals[s] = i;
        if (i < In) {
            const int v = sga[b * In + i];
            const float4 s0 = *(const float4*)(scoresv + ((size_t)nb * V1 + v) * NHn);
            const float4 s1 = *(const float4*)(scoresv + ((size_t)nb * V1 + v) * NHn + 4);
            sc[s][0] = s0.x; sc[s][1] = s0.y; sc[s][2] = s0.z; sc[s][3] = s0.w;
            sc[s][4] = s1.x; sc[s][5] = s1.y; sc[s][6] = s1.z; sc[s][7] = s1.w;
            if (v == 0) {
#pragma unroll
                for (int n = 0; n < NHn; ++n) sc[s][n] = -1e9f;
            }
        } else {
#pragma unroll
            for (int n = 0; n < NHn; ++n) sc[s][n] = -3.0e38f;
        }
    }

    float lm[NHn];
#pragma unroll
    for (int n = 0; n < NHn; ++n)
        lm[n] = fmaxf(fmaxf(sc[0][n], sc[1][n]), fmaxf(sc[2][n], sc[3][n]));
#pragma unroll
    for (int m = 1; m < 64; m <<= 1) {
#pragma unroll
        for (int n = 0; n < NHn; ++n) lm[n] = fmaxf(lm[n], __shfl_xor(lm[n], m, 64));
    }
    if (lane == 0) {
#pragma unroll
        for (int n = 0; n < NHn; ++n) red[wid * NHn + n] = lm[n];
    }
    __syncthreads();
    float M[NHn];
#pragma unroll
    for (int n = 0; n < NHn; ++n)
        M[n] = fmaxf(fmaxf(red[n], red[NHn + n]), fmaxf(red[2 * NHn + n], red[3 * NHn + n]));
    __syncthreads();

    float ls[NHn];
#pragma unroll
    for (int n = 0; n < NHn; ++n) ls[n] = 0.f;
#pragma unroll
    for (int s = 0; s < 4; ++s) {
#pragma unroll
        for (int n = 0; n < NHn; ++n) {
            sc[s][n] = expf(sc[s][n] - M[n]);
            ls[n] += sc[s][n];
        }
    }
#pragma unroll
    for (int m = 1; m < 64; m <<= 1) {
#pragma unroll
        for (int n = 0; n < NHn; ++n) ls[n] += __shfl_xor(ls[n], m, 64);
    }
    if (lane == 0) {
#pragma unroll
        for (int n = 0; n < NHn; ++n) red[wid * NHn + n] = ls[n];
    }
    __syncthreads();
    float inv[NHn];
#pragma unroll
    for (int n = 0; n < NHn; ++n) {
        const float S = red[n] + red[NHn + n] + red[2 * NHn + n] + red[3 * NHn + n];
        inv[n] = 1.0f / S;
    }

#pragma unroll
    for (int s = 0; s < 4; ++s) {
        if (ivals[s] < In) {
            float w = 0.f;
#pragma unroll
            for (int n = 0; n < NHn; ++n) w += sc[s][n] * inv[n];
            attn_out[((size_t)nb * Bn + b) * In + ivals[s]] = w;
        }
    }
}

// ---------------------------------------------------------------------------
// K3: emb[nb][b][e] = sum_i w[nb,b,i] * T[nb][sga[b,i]][e]
// ---------------------------------------------------------------------------
template <bool TBF>
__global__ __launch_bounds__(512)
void k_emb(const int* __restrict__ sga, const float* __restrict__ attn,
           const float* __restrict__ T, const ushort* __restrict__ Tbf,
           float* __restrict__ emb) {
    const int b  = blockIdx.x;
    const int nb = blockIdx.y;
    __shared__ int   sv[In];
    __shared__ float sw[In];
    __shared__ float pa[8][En];  // 16 KB
    for (int idx = threadIdx.x; idx < In; idx += 512) {
        sv[idx] = sga[b * In + idx];
        sw[idx] = attn[((size_t)nb * Bn + b) * In + idx];
    }
    __syncthreads();
    const int wave = threadIdx.x >> 6, lane = threadIdx.x & 63;
    float a[8];
#pragma unroll
    for (int j = 0; j < 8; ++j) a[j] = 0.f;

    if (TBF) {
        const ushort* Tb = Tbf + (size_t)nb * V1 * En;
#pragma unroll 10
        for (int g = 0; g < 100; ++g) {
            const int i = wave * 100 + g;
            const int v = sv[i];
            const float w = sw[i];
            const u16x8 t = *(const u16x8*)(Tb + (size_t)v * En + lane * 8);
#pragma unroll
            for (int j = 0; j < 8; ++j) a[j] += w * bf2f(t[j]);
        }
    } else {
        const float* Tb = T + (size_t)nb * V1 * En;
#pragma unroll 10
        for (int g = 0; g < 100; ++g) {
            const int i = wave * 100 + g;
            const int v = sv[i];
            const float w = sw[i];
            const float4* p = (const float4*)(Tb + (size_t)v * En) + lane * 2;
            const float4 t0 = p[0], t1 = p[1];
            a[0] += w * t0.x; a[1] += w * t0.y; a[2] += w * t0.z; a[3] += w * t0.w;
            a[4] += w * t1.x; a[5] += w * t1.y; a[6] += w * t1.z; a[7] += w * t1.w;
        }
    }
#pragma unroll
    for (int j = 0; j < 8; ++j) pa[wave][lane * 8 + j] = a[j];
    __syncthreads();
    const int t = threadIdx.x;
    float s = 0.f;
#pragma unroll
    for (int wv = 0; wv < 8; ++wv) s += pa[wv][t];
    emb[((size_t)nb * Bn + b) * En + t] = s;
}

// ---------------------------------------------------------------------------
// K4a: curr0 = relu(emb0 + can_emb[can]); hiddens[0] = curr0
// ---------------------------------------------------------------------------
__global__ __launch_bounds__(256)
void k_step0(const float* __restrict__ emb0, const int* __restrict__ can,
             const float* __restrict__ can_emb, float* __restrict__ cur,
             float* __restrict__ hid) {
    const int b = blockIdx.x;
    const int e0 = threadIdx.x * 2;
    const int c = can[b];
    float2 v = *(const float2*)(emb0 + (size_t)b * En + e0);
    const float2 ce = *(const float2*)(can_emb + (size_t)c * En + e0);
    v.x = fmaxf(v.x + ce.x, 0.f);
    v.y = fmaxf(v.y + ce.y, 0.f);
    *(float2*)(cur + (size_t)b * En + e0) = v;
    *(float2*)(hid + (size_t)b * En + e0) = v;
}

// ---------------------------------------------------------------------------
// K4b: curr = act(emb_i + prev @ Wh), K-split over 2 half-ranges,
// grid (b, 4 col-chunks) = 512 blocks.  act: 0=relu, 1=sigmoid
// ---------------------------------------------------------------------------
__global__ __launch_bounds__(256)
void k_step(const float* __restrict__ embi, const float* __restrict__ prev,
            const float* __restrict__ Whi, float* __restrict__ cur,
            float* __restrict__ hid, const int sig) {
    const int b = blockIdx.x, cc = blockIdx.y;
    __shared__ float pr[En];
    __shared__ float part[2][128];
    pr[threadIdx.x]       = prev[(size_t)b * En + threadIdx.x];
    pr[threadIdx.x + 256] = prev[(size_t)b * En + threadIdx.x + 256];
    __syncthreads();
    const int col = cc * 128 + (threadIdx.x & 127);
    const int kh  = threadIdx.x >> 7;
    float s = 0.f;
    const float* Wp = Whi + (size_t)(kh * 256) * En + col;
#pragma unroll 8
    for (int k = 0; k < 256; ++k) s += pr[kh * 256 + k] * Wp[(size_t)k * En];
    part[kh][threadIdx.x & 127] = s;
    __syncthreads();
    if (threadIdx.x < 128) {
        float a = part[0][threadIdx.x] + part[1][threadIdx.x] +
                  embi[(size_t)b * En + col];
        if (sig) a = 1.0f / (1.0f + expf(-a));
        else     a = fmaxf(a, 0.f);
        cur[(size_t)b * En + col] = a;
        hid[(size_t)b * En + col] = a;
    }
}

// ---------------------------------------------------------------------------
// K5: preds = curr3 @ Wfinal   [128,512]@[512,5000]
// ---------------------------------------------------------------------------
__global__ __launch_bounds__(256, 2)
void k_preds(const float* __restrict__ cur, const float* __restrict__ Wf,
             float* __restrict__ preds) {
    __shared__ float cs[32 * En];  // 64 KB
    const int nt = blockIdx.x;
    const int bt = blockIdx.y;
    for (int idx = threadIdx.x; idx < 32 * 128; idx += 256) {
        const int row = idx >> 7;
        const int c4  = (idx & 127) << 2;
        *(float4*)(cs + row * En + c4) =
            *(const float4*)(cur + (size_t)(bt * 32 + row) * En + c4);
    }
    __syncthreads();
    const int lane = threadIdx.x & 63;
    const int rgrp = threadIdx.x >> 6;
    const int col = nt * 64 + lane;
    float acc[8];
#pragma unroll
    for (int j = 0; j < 8; ++j) acc[j] = 0.f;
    const bool ok = (col < OUTn);
    for (int k = 0; k < En; k += 4) {
        float w0 = 0.f, w1 = 0.f, w2 = 0.f, w3 = 0.f;
        if (ok) {
            w0 = Wf[(size_t)(k + 0) * OUTn + col];
            w1 = Wf[(size_t)(k + 1) * OUTn + col];
            w2 = Wf[(size_t)(k + 2) * OUTn + col];
            w3 = Wf[(size_t)(k + 3) * OUTn + col];
        }
#pragma unroll
        for (int j = 0; j < 8; ++j) {
            const float4 cv = *(const float4*)(cs + (rgrp * 8 + j) * En + k);
            acc[j] += cv.x * w0 + cv.y * w1 + cv.z * w2 + cv.w * w3;
        }
    }
    if (ok) {
#pragma unroll
        for (int j = 0; j < 8; ++j)
            preds[(size_t)(bt * 32 + rgrp * 8 + j) * OUTn + col] = acc[j];
    }
}

// ---------------------------------------------------------------------------
extern "C" void kernel_launch(void* const* d_in, const int* in_sizes, int n_in,
                              void* d_out, int out_size, void* d_ws, size_t ws_size,
                              hipStream_t stream) {
    const int*   sga     = (const int*)d_in[0];
    const int*   can     = (const int*)d_in[1];
    const float* T       = (const float*)d_in[2];
    const float* Wk      = (const float*)d_in[3];
    const float* bk      = (const float*)d_in[4];
    const float* Wq      = (const float*)d_in[5];
    // d_in[6] = bq: unused — constant over softmax axis, cancels exactly
    const float* can_emb = (const float*)d_in[7];
    const float* Wh      = (const float*)d_in[8];
    const float* Wf      = (const float*)d_in[9];

    float* out = (float*)d_out;
    float* ws  = (float*)d_ws;

    // workspace layout (floats; all 16B-aligned)
    float* scoresv = ws;                                // NB*V1*NH   = 608032
    float* embw    = scoresv + (size_t)NBn * V1 * NHn;  // NB*B*E     = 262144
    float* cur0    = embw + (size_t)NBn * Bn * En;      // B*E
    float* cur1    = cur0 + (size_t)Bn * En;            // B*E
    float* wqt     = cur1 + (size_t)Bn * En;            // NB*NH*E    = 16384
    ushort* Wkt    = (ushort*)(wqt + (size_t)NBn * NHn * En); // NB*E*E bf16
    ushort* Tbf    = Wkt + (size_t)NBn * En * En;       // NB*V1*E bf16 = 78 MB
    const size_t need_full =
        ((size_t)NBn * V1 * NHn + (size_t)NBn * Bn * En + 2 * (size_t)Bn * En +
         (size_t)NBn * NHn * En) * 4 +
        (size_t)NBn * En * En * 2 + (size_t)NBn * V1 * En * 2;
    const bool useTbf = (ws_size >= need_full);

    float* preds_out = out;
    float* attn_out  = out + OFF_ATTN;
    float* hid_out   = out + OFF_HID;

    // K0: Wk -> bf16 K-panel-tiled; K0q: Wq -> transposed f32
    k_prep<<<dim3(8, 8, NBn), 256, 0, stream>>>(Wk, Wkt);
    k_prepq<<<NBn, 256, 0, stream>>>(Wq, wqt);
    if (useTbf) {
        // K0b: T -> bf16 (streaming, full BW)
        const long long n8 = (long long)NBn * V1 * En / 8;
        k_cvt<<<4096, 256, 0, stream>>>(T, Tbf, n8);
        // K1: all-glds keys-GEMM + scores epilogue
        k_scores_fast<<<dim3((V1 + 63) / 64, NBn), 256, 0, stream>>>(
            Tbf, Wkt, bk, wqt, scoresv);
    } else {
        k_scores_slow<<<dim3((V1 + 63) / 64, NBn), 256, 0, stream>>>(
            T, Wkt, bk, Wq, scoresv);
    }
    // K2: softmax + head-sum -> attns (directly to d_out)
    k_softmax<<<dim3(Bn, NBn), 256, 0, stream>>>(sga, scoresv, attn_out);
    // K3: weighted embedding sums (bf16 gather if Tbf available)
    if (useTbf)
        k_emb<true><<<dim3(Bn, NBn), 512, 0, stream>>>(sga, attn_out, T, Tbf, embw);
    else
        k_emb<false><<<dim3(Bn, NBn), 512, 0, stream>>>(sga, attn_out, T, Tbf, embw);
    // K4: residual chain
    k_step0<<<Bn, 256, 0, stream>>>(embw, can, can_emb, cur0, hid_out);
    k_step<<<dim3(Bn, 4), 256, 0, stream>>>(embw + 1 * Bn * En, cur0,
                                            Wh + 0 * En * En, cur1,
                                            hid_out + 1 * (size_t)Bn * En, 0);
    k_step<<<dim3(Bn, 4), 256, 0, stream>>>(embw + 2 * Bn * En, cur1,
                                            Wh + 1 * En * En, cur0,
                                            hid_out + 2 * (size_t)Bn * En, 0);
    k_step<<<dim3(Bn, 4), 256, 0, stream>>>(embw + 3 * Bn * En, cur0,
                                            Wh + 2 * En * En, cur1,
                                            hid_out + 3 * (size_t)Bn * En, 1);
    // K5: final projection
    k_preds<<<dim3((OUTn + 63) / 64, Bn / 32), 256, 0, stream>>>(cur1, Wf, preds_out);
}